// Round 13
// baseline (424.550 us; speedup 1.0000x reference)
//
#include <hip/hip_runtime.h>
#include <stdint.h>

// ContextualAttention on MI355X. Inputs/outputs float32; correlation logits via
// 2-term f16 split MFMA (A=[x_hi|x_lo], B=w_hi), bf16 MFMA elsewhere, fp32 softmax.
//
// Round 13: branchless fuse_sm. Yt stored guard-padded (row stride 2306: 2304 data +
// 2 zero guards, shared as next row's -1 slot; 4 front guards/item) so the 9-diagonal
// gather is 9 unconditional f32x4 loads + 0/1 mask multiply for the 2 wrap lanes.
// Kills the per-lane vector/scalar dual-path divergence (every wave had wrap lanes).
//
// ws layout (bytes), total <= 169,869,312:
//  Ytp  [0, 85008448)          f32 padded logits (phase1; item stride 21,252,112)
//  Pt2  [85008448, +46080000)  bf16 padded softmax
//  Rwa  [131088448, +18874368) bf16 4x4 patch bank
//  Wn   [138018816, +10616832) f16 (phase1 only, dead after gemm; overlapped by Rwa tail use ordering)
//  Xb   [148635648, +21233664) f16 (phase1 only)
//  phase2 over dead Ytp: T [0, 20971520) | Ybt2 [20971520) | Y1t2 [25888768)
//                        | Wp1 [30806016) | Wp2 [30879744)

#define YI 5313028ull   // floats per Yt item incl 4 front guards (4 + 2304*2306)
typedef __attribute__((ext_vector_type(8))) short short8;
typedef __attribute__((ext_vector_type(8))) _Float16 half8;
typedef __attribute__((ext_vector_type(4))) float f32x4;
typedef __attribute__((ext_vector_type(4), aligned(4))) float f32x4u;
typedef __attribute__((ext_vector_type(4))) short s16x4;

#if defined(__has_builtin)
#if __has_builtin(__builtin_amdgcn_global_load_lds)
#define HAVE_GLL 1
#endif
#endif

#ifdef HAVE_GLL
typedef const __attribute__((address_space(1))) void* gp1_t;
typedef __attribute__((address_space(3))) void* lp3_t;
__device__ __forceinline__ void gl_lds16(const void* g, void* l){
  __builtin_amdgcn_global_load_lds((gp1_t)g, (lp3_t)l, 16, 0, 0);
}
#else
__device__ __forceinline__ void gl_lds16(const void* g, void* l){
  *(short8*)l = *(const short8*)g;
}
#endif

__device__ __forceinline__ float b2f(uint16_t u){
  union { uint32_t i; float f; } v; v.i = ((uint32_t)u) << 16; return v.f;
}
__device__ __forceinline__ uint16_t f2b(float f){
  uint32_t x = __float_as_uint(f);
  uint32_t r = (x + 0x7FFFu + ((x >> 16) & 1u)) >> 16;
  return (uint16_t)r;
}
__device__ __forceinline__ uint16_t f2h(float f){
  union { _Float16 h; uint16_t u; } v; v.h = (_Float16)f; return v.u;
}
__device__ __forceinline__ float h2f(uint16_t u){
  union { uint16_t u; _Float16 h; } v; v.u = u; return (float)v.h;
}
__device__ __forceinline__ int gfun(int x, int d){
  int t = (x % 48) * 48 + (x / 48) + d;
  if ((unsigned)t >= 2304u) return -1;
  return (t % 48) * 48 + (t / 48);
}

// ---------------- prep kernels (LDS-staged coalesced stores) ----------------

__global__ void k_build_wn(const float* __restrict__ bsrc, uint16_t* __restrict__ wn){
  __shared__ uint16_t lds[576];
  int o = blockIdx.x, item = blockIdx.y, c = threadIdx.x;
  int m = o * 64 + c;
  int c0 = m / 2304, rem = m % 2304, i = rem / 48, j = rem % 48;
  const float* bp = bsrc + ((size_t)item * 64 + c0) * 9216;
  float v[9]; float ss = 0.f;
#pragma unroll
  for (int p = 0; p < 3; p++)
#pragma unroll
    for (int q = 0; q < 3; q++){
      int y = i + p - 1, x = j + q - 1;
      float val = 0.f;
      if ((unsigned)y < 48u && (unsigned)x < 48u) val = bp[y * 192 + x * 2];
      v[p * 3 + q] = val; ss += val * val;
    }
#pragma unroll
  for (int off = 32; off > 0; off >>= 1) ss += __shfl_xor(ss, off, 64);
  float inv = 1.f / fmaxf(sqrtf(ss), 1e-4f);
#pragma unroll
  for (int t = 0; t < 9; t++) lds[c * 9 + t] = f2h(v[t] * inv);
  __syncthreads();
  uint32_t* d32 = (uint32_t*)(wn + ((size_t)item * 2304 + o) * 576);
  const uint32_t* s32 = (const uint32_t*)lds;
#pragma unroll
  for (int k = 0; k < 5; k++){
    int idx = k * 64 + c;
    if (idx < 288) d32[idx] = s32[idx];
  }
}

__global__ void k_build_x(const float* __restrict__ fsrc, uint16_t* __restrict__ xb){
  __shared__ uint16_t lds[1152];
  int s = blockIdx.x, item = blockIdx.y, c = threadIdx.x;
  int y = s / 48, x = s % 48;
  const float* fp = fsrc + ((size_t)item * 64 + c) * 9216;
#pragma unroll
  for (int p = 0; p < 3; p++)
#pragma unroll
    for (int q = 0; q < 3; q++){
      int yy = y + p - 1, xx = x + q - 1;
      float val = 0.f;
      if ((unsigned)yy < 48u && (unsigned)xx < 48u) val = fp[yy * 192 + xx * 2];
      uint16_t hi = f2h(val);
      int t = p * 3 + q;
      lds[c * 9 + t] = hi;
      lds[576 + c * 9 + t] = f2h(val - h2f(hi));
    }
  __syncthreads();
  uint32_t* d32 = (uint32_t*)(xb + ((size_t)item * 2304 + s) * 1152);
  const uint32_t* s32 = (const uint32_t*)lds;
#pragma unroll
  for (int k = 0; k < 9; k++){
    int idx = k * 64 + c;
    d32[idx] = s32[idx];
  }
}

// zero the guard columns (2304,2305 of each row) + 4 front guards per item
__global__ void k_zero_guard(float* __restrict__ Yt){
  int t = blockIdx.x * 256 + threadIdx.x;   // [0, 9216)
  int item = t / 2304, row = t % 2304;
  float* yp = Yt + (size_t)item * YI + 4;
  yp[(size_t)row * 2306 + 2304] = 0.f;
  yp[(size_t)row * 2306 + 2305] = 0.f;
  if (row < 4) (Yt + (size_t)item * YI)[row] = 0.f;
}

// ---------------- correlation GEMM: Yt[s][o] = X @ Wn^T (guard-padded C) ----------------

__launch_bounds__(256)
__global__ void k_gemm_corr(const uint16_t* __restrict__ A, const uint16_t* __restrict__ B,
                            float* __restrict__ Cd){
  __shared__ __align__(16) uint16_t As1[128 * 32];
  __shared__ __align__(16) uint16_t As2[128 * 32];
  __shared__ __align__(16) uint16_t Bs[128 * 32];
  int item = blockIdx.z;
  int n0 = blockIdx.x * 128, m0 = blockIdx.y * 128;
  const uint16_t* Ap = A + (size_t)item * 2304 * 1152;
  const uint16_t* Bp = B + (size_t)item * 2304 * 576;
  int tid = threadIdx.x;
  int wave = tid >> 6, lane = tid & 63, lm = lane & 15, lg = lane >> 4;
  int wy = wave >> 1, wx = wave & 1;
  int swl = (lg ^ ((lm >> 2) & 3)) * 8;
  f32x4 acc[4][4] = {};
  for (int kt = 0; kt < 18; kt++){
    int kb = kt * 32;
#pragma unroll
    for (int c = tid; c < 1536; c += 256){
      int half = c >> 9;            // 0=A_hi, 1=A_lo, 2=B
      int cc = c & 511;
      int row = cc >> 2, j = cc & 3;
      int sw = (j ^ ((row >> 2) & 3)) * 8;
      if (half == 0)
        gl_lds16(&Ap[(size_t)(m0 + row) * 1152 + kb + sw], &As1[cc * 8]);
      else if (half == 1)
        gl_lds16(&Ap[(size_t)(m0 + row) * 1152 + 576 + kb + sw], &As2[cc * 8]);
      else
        gl_lds16(&Bp[(size_t)(n0 + row) * 576 + kb + sw], &Bs[cc * 8]);
    }
    __syncthreads();
    half8 af1[4], af2[4], bf[4];
#pragma unroll
    for (int i = 0; i < 4; i++){
      af1[i] = *(const half8*)&As1[(wy * 64 + i * 16 + lm) * 32 + swl];
      af2[i] = *(const half8*)&As2[(wy * 64 + i * 16 + lm) * 32 + swl];
      bf[i]  = *(const half8*)&Bs[(wx * 64 + i * 16 + lm) * 32 + swl];
    }
#pragma unroll
    for (int i = 0; i < 4; i++)
#pragma unroll
      for (int j = 0; j < 4; j++){
        acc[i][j] = __builtin_amdgcn_mfma_f32_16x16x32_f16(af1[i], bf[j], acc[i][j], 0, 0, 0);
        acc[i][j] = __builtin_amdgcn_mfma_f32_16x16x32_f16(af2[i], bf[j], acc[i][j], 0, 0, 0);
      }
    __syncthreads();
  }
  float* Cp = Cd + (size_t)item * YI + 4;
#pragma unroll
  for (int i = 0; i < 4; i++){
    int rb = m0 + wy * 64 + i * 16 + lg * 4;
#pragma unroll
    for (int j = 0; j < 4; j++){
      int cc = n0 + wx * 64 + j * 16 + lm;
#pragma unroll
      for (int r = 0; r < 4; r++)
        Cp[(size_t)(rb + r) * 2306 + cc] = acc[i][j][r];
    }
  }
}

// ---------------- merged fuse + softmax (branchless guarded gather) ----------------

__global__ void k_fuse_sm(const float* __restrict__ Yt, uint16_t* __restrict__ pt2){
  __shared__ float red[4];
  int bx = blockIdx.x;
  int s = (bx & 7) * 288 + (bx >> 3);   // XCD k owns contiguous s-window
  int item = blockIdx.y, t = threadIdx.x;
  const float* yp = Yt + (size_t)item * YI + 4;
  int rs[3]; rs[0] = gfun(s, -1); rs[1] = s; rs[2] = gfun(s, 1);
  int nact = (t < 64) ? 3 : 2;
  f32x4u v[3];
  for (int u = 0; u < 3; u++){
    f32x4u acc = {0.f, 0.f, 0.f, 0.f};
    if (u < nact){
      int g = t + u * 256;
      int o0 = 4 * g, orr = o0 / 48, oc0 = o0 % 48;
#pragma unroll
      for (int dd = 0; dd < 3; dd++){
        int a0 = rs[dd];
        if (a0 < 0) continue;               // block-uniform
        int d = dd - 1;
        int base; f32x4u mv = {1.f, 1.f, 1.f, 1.f};
        if (d == 0) base = o0;
        else {
          int tor = orr + d;
          if ((unsigned)tor < 48u) base = tor * 48 + oc0;
          else if (tor < 0){ base = 2255 + oc0; if (oc0 == 0) mv[0] = 0.f; }
          else { base = oc0 + 1; if (oc0 == 44) mv[3] = 0.f; }
        }
#pragma unroll
        for (int e = -1; e <= 1; e++){
          int a = a0 + e;
          if ((unsigned)a >= 2304u) continue;   // block-uniform
          const float* rowp = yp + (size_t)a * 2306;
          f32x4u x = *(const f32x4u*)&rowp[base + e];  // guards make [-1,2304] safe+zero
          acc += x * mv;
        }
      }
    }
    v[u] = acc;
  }
  float mx = -3.4e38f;
  for (int u = 0; u < nact; u++)
#pragma unroll
    for (int i = 0; i < 4; i++) mx = fmaxf(mx, v[u][i]);
#pragma unroll
  for (int off = 32; off > 0; off >>= 1) mx = fmaxf(mx, __shfl_xor(mx, off, 64));
  if ((t & 63) == 0) red[t >> 6] = mx;
  __syncthreads();
  mx = fmaxf(fmaxf(red[0], red[1]), fmaxf(red[2], red[3]));
  float sum = 0.f;
  for (int u = 0; u < nact; u++)
#pragma unroll
    for (int i = 0; i < 4; i++){ v[u][i] = __expf(10.f * (v[u][i] - mx)); sum += v[u][i]; }
#pragma unroll
  for (int off = 32; off > 0; off >>= 1) sum += __shfl_xor(sum, off, 64);
  __syncthreads();
  if ((t & 63) == 0) red[t >> 6] = sum;
  __syncthreads();
  float inv = 1.f / (red[0] + red[1] + red[2] + red[3]);
  uint16_t* pr = pt2 + ((size_t)item * 2500 + (size_t)(s / 48 + 1) * 50 + (s % 48) + 1) * 2304;
  for (int u = 0; u < nact; u++){
    s16x4 w;
#pragma unroll
    for (int i = 0; i < 4; i++) w[i] = (short)f2b(v[u][i] * inv);
    *(s16x4*)&pr[4 * (t + u * 256)] = w;
  }
}

__global__ void k_zero_pad(uint16_t* __restrict__ pt2){
  int p = blockIdx.x, item = blockIdx.y, t = threadIdx.x;
  int sy, sx;
  if (p < 50){ sy = 0; sx = p; }
  else if (p < 100){ sy = 49; sx = p - 50; }
  else if (p < 148){ sy = p - 99; sx = 0; }
  else { sy = p - 147; sx = 49; }
  uint16_t* pr = pt2 + ((size_t)item * 2500 + sy * 50 + sx) * 2304;
  short8 z = {};
  for (int c = t; c < 288; c += 256) *(short8*)&pr[c * 8] = z;
}

// ---------------- raw 4x4 patch bank, layout [item][tap16][co][l] ----------------

__global__ void k_build_rwa(const float* __restrict__ bsrc, uint16_t* __restrict__ rwa){
  __shared__ uint16_t tile[64][66];
  int item = blockIdx.y, l0 = blockIdx.x * 64;
  const float* bp = bsrc + (size_t)item * 64 * 9216;
  int wave = threadIdx.x >> 6, lane = threadIdx.x & 63;
  for (int tap = 0; tap < 16; tap++){
    int py = tap >> 2, qx = tap & 3;
#pragma unroll
    for (int step = 0; step < 16; step++){
      int lsub = wave * 16 + step;
      int l = l0 + lsub, co = lane;
      int m = l * 64 + co;
      int c0 = m / 2304, rem = m % 2304, i = rem / 48, jj = rem % 48;
      int Y = 2 * i + py - 1, X = 2 * jj + qx - 1;
      float val = 0.f;
      if ((unsigned)Y < 96u && (unsigned)X < 96u) val = bp[(size_t)c0 * 9216 + Y * 96 + X];
      tile[lsub][co] = f2b(val);
    }
    __syncthreads();
#pragma unroll
    for (int step = 0; step < 16; step++){
      int co = wave * 16 + step;
      rwa[(((size_t)item * 16 + tap) * 64 + co) * 2304 + l0 + lane] = tile[lane][co];
    }
    __syncthreads();
  }
}

// ---------------- deconv GEMM: T = Rwa . Pt2^T, M=1024,N=2560,K=2304, BK=64 ----------------

__launch_bounds__(256)
__global__ void k_deconv2(const uint16_t* __restrict__ rwa, const uint16_t* __restrict__ pt2,
                          uint16_t* __restrict__ T){
  __shared__ __align__(16) uint16_t As[128 * 64];
  __shared__ __align__(16) uint16_t Bs[128 * 64];
  int item = blockIdx.z;
  int n0 = blockIdx.x * 128, m0 = blockIdx.y * 128;
  const uint16_t* Ap = rwa + (size_t)item * 1024 * 2304;
  const uint16_t* Bp = pt2 + (size_t)item * 2500 * 2304;   // rows >= 2500 read garbage; discarded
  int tid = threadIdx.x;
  int wave = tid >> 6, lane = tid & 63, lm = lane & 15, lg = lane >> 4;
  int wy = wave >> 1, wx = wave & 1;
  f32x4 acc[4][4] = {};
  for (int kt = 0; kt < 36; kt++){
    int kb = kt * 64;
#pragma unroll
    for (int c = tid; c < 2048; c += 256){
      int cc = c & 1023;
      int row = cc >> 3, pj = cc & 7;
      int jl = pj ^ (row & 7);           // 8-chunk XOR swizzle
      if (c < 1024)
        gl_lds16(&Ap[(size_t)(m0 + row) * 2304 + kb + jl * 8], &As[cc * 8]);
      else
        gl_lds16(&Bp[(size_t)(n0 + row) * 2304 + kb + jl * 8], &Bs[cc * 8]);
    }
    __syncthreads();
#pragma unroll
    for (int k2 = 0; k2 < 2; k2++){
      short8 af[4], bf[4];
#pragma unroll
      for (int i = 0; i < 4; i++){
        int rowa = wy * 64 + i * 16 + lm;
        int pja = (k2 * 4 + lg) ^ (lm & 7);
        af[i] = *(const short8*)&As[rowa * 64 + pja * 8];
        int rowb = wx * 64 + i * 16 + lm;
        bf[i] = *(const short8*)&Bs[rowb * 64 + pja * 8];
      }
#pragma unroll
      for (int i = 0; i < 4; i++)
#pragma unroll
        for (int j = 0; j < 4; j++)
          acc[i][j] = __builtin_amdgcn_mfma_f32_16x16x32_bf16(af[i], bf[j], acc[i][j], 0, 0, 0);
    }
    __syncthreads();
  }
  uint16_t* Tp = T + (size_t)item * 1024 * 2560;
#pragma unroll
  for (int i = 0; i < 4; i++){
    int rb = m0 + wy * 64 + i * 16 + lg * 4;
#pragma unroll
    for (int j = 0; j < 4; j++){
      int cc = n0 + wx * 64 + j * 16 + lm;
#pragma unroll
      for (int r = 0; r < 4; r++)
        Tp[(size_t)(rb + r) * 2560 + cc] = f2b(acc[i][j][r]);
    }
  }
}

// gather 4 taps per output pixel -> padded Ybt2[98][98][64] interior
__global__ void k_dred2(const uint16_t* __restrict__ T, uint16_t* __restrict__ ybt2){
  int my = blockIdx.x, phase = blockIdx.y, item = blockIdx.z;
  int co = threadIdx.x;
  int fy = phase >> 1, fx = phase & 1;
  const uint16_t* Tp = T + (size_t)item * 1024 * 2560;
  uint16_t* op = ybt2 + (size_t)item * 98 * 98 * 64;
  for (int mx = 0; mx < 48; mx++){
    float acc = 0.f;
#pragma unroll
    for (int ay = 0; ay < 2; ay++)
#pragma unroll
      for (int ax = 0; ax < 2; ax++){
        int tap = (3 - fy - 2 * ay) * 4 + (3 - fx - 2 * ax);
        int sp = (my + ay + fy) * 50 + (mx + ax + fx);
        acc += b2f(Tp[(size_t)(tap * 64 + co) * 2560 + sp]);
      }
    int Y = 2 * my + fy + 1, X = 2 * mx + fx + 1;
    op[((size_t)Y * 98 + X) * 64 + co] = f2b(acc * 0.25f);
  }
}

__global__ void k_zero2(uint16_t* __restrict__ p){
  size_t i = ((size_t)blockIdx.x * 256 + threadIdx.x) * 8;
  short8 z = {};
  *(short8*)&p[i] = z;
}

// ---------------- final 3x3 convs (direct from padded layout) ----------------

__global__ void k_pack_w(const float* __restrict__ w1, const float* __restrict__ w2,
                         uint16_t* __restrict__ p1, uint16_t* __restrict__ p2){
  int i = blockIdx.x * 256 + threadIdx.x;
  if (i < 36864){
    int co = i / 576, rem = i % 576, ci = rem / 9, t = rem % 9;
    int di = co * 576 + t * 64 + ci;
    p1[di] = f2b(w1[i]); p2[di] = f2b(w2[i]);
  }
}

__launch_bounds__(256)
__global__ void k_conv_gemm2(const uint16_t* __restrict__ Wp, const uint16_t* __restrict__ Src,
                             const float* __restrict__ bias,
                             uint16_t* __restrict__ dst16, float* __restrict__ dst32){
  __shared__ __align__(16) uint16_t As[64 * 32];
  __shared__ __align__(16) uint16_t Bs[128 * 32];
  int n0 = blockIdx.x * 128, item = blockIdx.z;
  int tid = threadIdx.x, wave = tid >> 6, lane = tid & 63, lm = lane & 15, lg = lane >> 4;
  int swl = (lg ^ ((lm >> 2) & 3)) * 8;
  const uint16_t* Bp = Src + (size_t)item * 98 * 98 * 64;
  f32x4 acc[4][2] = {};
  for (int kt = 0; kt < 18; kt++){
    int t = kt >> 1, cb = (kt & 1) * 32;
    int py = t / 3, qx = t % 3;
#pragma unroll
    for (int c = tid; c < 768; c += 256){
      if (c < 256){
        int row = c >> 2, j = c & 3;
        int sw = (j ^ ((row >> 2) & 3)) * 8;
        gl_lds16(&Wp[(size_t)row * 576 + kt * 32 + sw], &As[c * 8]);
      } else {
        int cc = c - 256; int row = cc >> 2, j = cc & 3;
        int sw = (j ^ ((row >> 2) & 3)) * 8;
        int n = n0 + row; int y = n / 96, x = n % 96;
        gl_lds16(&Bp[((size_t)(y + py) * 98 + (x + qx)) * 64 + cb + sw], &Bs[cc * 8]);
      }
    }
    __syncthreads();
    short8 af[4], bf[2];
#pragma unroll
    for (int i = 0; i < 4; i++) af[i] = *(const short8*)&As[(i * 16 + lm) * 32 + swl];
#pragma unroll
    for (int j = 0; j < 2; j++) bf[j] = *(const short8*)&Bs[(wave * 32 + j * 16 + lm) * 32 + swl];
#pragma unroll
    for (int i = 0; i < 4; i++)
#pragma unroll
      for (int j = 0; j < 2; j++)
        acc[i][j] = __builtin_amdgcn_mfma_f32_16x16x32_bf16(af[i], bf[j], acc[i][j], 0, 0, 0);
    __syncthreads();
  }
  if (dst32){
#pragma unroll
    for (int i = 0; i < 4; i++)
#pragma unroll
      for (int j = 0; j < 2; j++){
        int n = n0 + wave * 32 + j * 16 + lm;
#pragma unroll
        for (int r = 0; r < 4; r++){
          int co = i * 16 + lg * 4 + r;
          dst32[((size_t)item * 64 + co) * 9216 + n] = acc[i][j][r] + bias[co];
        }
      }
  } else {
    uint16_t* dp = dst16 + (size_t)item * 98 * 98 * 64;
#pragma unroll
    for (int i = 0; i < 4; i++)
#pragma unroll
      for (int j = 0; j < 2; j++){
        int n = n0 + wave * 32 + j * 16 + lm;
        int y = n / 96, x = n % 96;
        int co0 = i * 16 + lg * 4;
        s16x4 w;
#pragma unroll
        for (int r = 0; r < 4; r++) w[r] = (short)f2b(acc[i][j][r] + bias[co0 + r]);
        *(s16x4*)&dp[((size_t)(y + 1) * 98 + (x + 1)) * 64 + co0] = w;
      }
  }
}

// ---------------- launch ----------------

extern "C" void kernel_launch(void* const* d_in, const int* in_sizes, int n_in,
                              void* d_out, int out_size, void* d_ws, size_t ws_size,
                              hipStream_t stream){
  const float* f  = (const float*)d_in[0];
  const float* b  = (const float*)d_in[1];
  const float* w1 = (const float*)d_in[2];
  const float* b1 = (const float*)d_in[3];
  const float* w2 = (const float*)d_in[4];
  const float* b2 = (const float*)d_in[5];
  char* ws = (char*)d_ws;
  // phase1
  float*    Yt   = (float*)ws;                          // 85,008,448 B (guard-padded)
  uint16_t* Wn   = (uint16_t*)(ws + 138018816ull);      // 10,616,832 B (f16 w_hi, stride 576)
  uint16_t* Xb   = (uint16_t*)(ws + 148635648ull);      // 21,233,664 B (f16 [hi|lo], stride 1152)
  uint16_t* Pt2  = (uint16_t*)(ws + 85008448ull);       // 46,080,000 B
  uint16_t* Rwa  = (uint16_t*)(ws + 131088448ull);      // 18,874,368 B (over dead Wn after gemm)
  // phase2 (over dead Yt)
  uint16_t* T    = (uint16_t*)ws;                       // 20,971,520 B
  uint16_t* Ybt2 = (uint16_t*)(ws + 20971520ull);       //  4,917,248 B
  uint16_t* Y1t2 = (uint16_t*)(ws + 25888768ull);       //  4,917,248 B
  uint16_t* Wp1  = (uint16_t*)(ws + 30806016ull);       //     73,728 B
  uint16_t* Wp2  = (uint16_t*)(ws + 30879744ull);       //     73,728 B
  float*    out  = (float*)d_out;

  k_build_wn<<<dim3(2304, 4), 64, 0, stream>>>(b, Wn);
  k_build_x<<<dim3(2304, 4), 64, 0, stream>>>(f, Xb);
  k_zero_guard<<<dim3(36), 256, 0, stream>>>(Yt);
  k_gemm_corr<<<dim3(18, 18, 4), 256, 0, stream>>>(Xb, Wn, Yt);   // A=Xb (1152) -> rows=s
  k_zero_pad<<<dim3(196, 4), 256, 0, stream>>>(Pt2);
  k_build_rwa<<<dim3(36, 4), 256, 0, stream>>>(b, Rwa);           // Wn dead now
  k_fuse_sm<<<dim3(2304, 4), 256, 0, stream>>>(Yt, Pt2);
  k_deconv2<<<dim3(20, 8, 4), 256, 0, stream>>>(Rwa, Pt2, T);     // Yt dead now
  k_zero2<<<dim3(2401), 256, 0, stream>>>(Ybt2);                  // zeroes Ybt2+Y1t2 (contiguous)
  k_dred2<<<dim3(48, 4, 4), 64, 0, stream>>>(T, Ybt2);
  k_pack_w<<<dim3(144), 256, 0, stream>>>(w1, w2, Wp1, Wp2);
  k_conv_gemm2<<<dim3(72, 1, 4), 256, 0, stream>>>(Wp1, Ybt2, b1, Y1t2, nullptr);
  k_conv_gemm2<<<dim3(72, 1, 4), 256, 0, stream>>>(Wp2, Y1t2, b2, nullptr, out);
}

// Round 14
// 368.980 us; speedup vs baseline: 1.1506x; 1.1506x over previous
//
#include <hip/hip_runtime.h>
#include <stdint.h>

// ContextualAttention on MI355X. Inputs/outputs float32; correlation logits via
// 2-term f16 split MFMA (A=[x_hi|x_lo], B=w_hi), bf16 MFMA elsewhere, fp32 softmax.
//
// Round 14:
//  - Yt pad stride 2306->2320 (rows 64B-aligned; 16 front guards -> item stride % 64 == 0)
//  - XCD-rectangle swizzle in k_gemm_corr (flat 1296) and k_deconv2 (flat 640):
//    XCD k = blk%8 owns (item k/2, n-half k&1, all m) -> kills cross-XCD tile re-fetch
//  - zero_guard+zero_pad+zero2+pack_w merged into k_misc (13 -> 10 launches);
//    Ybt2/Y1t2/Wp1/Wp2 relocated outside Yt so k_misc can run right after corr
//
// ws layout (bytes), budget 169,869,312:
//  Yt   [0, 85524736)            f32 padded logits (item stride 21,381,184; row 2320)
//  Wn   [85524736, +10616832)    f16 w_hi (phase1; dead after corr)
//  Xb   [96141568, +21233664)    f16 [hi|lo] (phase1; dead after corr)
//  Pt2  [85524736, +46080000)    bf16 padded softmax (over dead Wn/Xb)
//  Rwa  [131604736, +18874368)   bf16 4x4 patch bank
//  Ybt2 [150479104, +4917248)    bf16 padded deconv out
//  Y1t2 [155396352, +4917248)    bf16 padded conv1 out
//  Wp1  [160313600, +73728)  Wp2 [160387328, +73728)
//  phase2 over dead Yt: T [0, 20971520)

#define YI 5345296ull   // floats per Yt item: 16 front guards + 2304*2320
typedef __attribute__((ext_vector_type(8))) short short8;
typedef __attribute__((ext_vector_type(8))) _Float16 half8;
typedef __attribute__((ext_vector_type(4))) float f32x4;
typedef __attribute__((ext_vector_type(4), aligned(4))) float f32x4u;
typedef __attribute__((ext_vector_type(4))) short s16x4;

#if defined(__has_builtin)
#if __has_builtin(__builtin_amdgcn_global_load_lds)
#define HAVE_GLL 1
#endif
#endif

#ifdef HAVE_GLL
typedef const __attribute__((address_space(1))) void* gp1_t;
typedef __attribute__((address_space(3))) void* lp3_t;
__device__ __forceinline__ void gl_lds16(const void* g, void* l){
  __builtin_amdgcn_global_load_lds((gp1_t)g, (lp3_t)l, 16, 0, 0);
}
#else
__device__ __forceinline__ void gl_lds16(const void* g, void* l){
  *(short8*)l = *(const short8*)g;
}
#endif

__device__ __forceinline__ float b2f(uint16_t u){
  union { uint32_t i; float f; } v; v.i = ((uint32_t)u) << 16; return v.f;
}
__device__ __forceinline__ uint16_t f2b(float f){
  uint32_t x = __float_as_uint(f);
  uint32_t r = (x + 0x7FFFu + ((x >> 16) & 1u)) >> 16;
  return (uint16_t)r;
}
__device__ __forceinline__ uint16_t f2h(float f){
  union { _Float16 h; uint16_t u; } v; v.h = (_Float16)f; return v.u;
}
__device__ __forceinline__ float h2f(uint16_t u){
  union { uint16_t u; _Float16 h; } v; v.u = u; return (float)v.h;
}
__device__ __forceinline__ int gfun(int x, int d){
  int t = (x % 48) * 48 + (x / 48) + d;
  if ((unsigned)t >= 2304u) return -1;
  return (t % 48) * 48 + (t / 48);
}

// ---------------- prep kernels (LDS-staged coalesced stores) ----------------

__global__ void k_build_wn(const float* __restrict__ bsrc, uint16_t* __restrict__ wn){
  __shared__ uint16_t lds[576];
  int o = blockIdx.x, item = blockIdx.y, c = threadIdx.x;
  int m = o * 64 + c;
  int c0 = m / 2304, rem = m % 2304, i = rem / 48, j = rem % 48;
  const float* bp = bsrc + ((size_t)item * 64 + c0) * 9216;
  float v[9]; float ss = 0.f;
#pragma unroll
  for (int p = 0; p < 3; p++)
#pragma unroll
    for (int q = 0; q < 3; q++){
      int y = i + p - 1, x = j + q - 1;
      float val = 0.f;
      if ((unsigned)y < 48u && (unsigned)x < 48u) val = bp[y * 192 + x * 2];
      v[p * 3 + q] = val; ss += val * val;
    }
#pragma unroll
  for (int off = 32; off > 0; off >>= 1) ss += __shfl_xor(ss, off, 64);
  float inv = 1.f / fmaxf(sqrtf(ss), 1e-4f);
#pragma unroll
  for (int t = 0; t < 9; t++) lds[c * 9 + t] = f2h(v[t] * inv);
  __syncthreads();
  uint32_t* d32 = (uint32_t*)(wn + ((size_t)item * 2304 + o) * 576);
  const uint32_t* s32 = (const uint32_t*)lds;
#pragma unroll
  for (int k = 0; k < 5; k++){
    int idx = k * 64 + c;
    if (idx < 288) d32[idx] = s32[idx];
  }
}

__global__ void k_build_x(const float* __restrict__ fsrc, uint16_t* __restrict__ xb){
  __shared__ uint16_t lds[1152];
  int s = blockIdx.x, item = blockIdx.y, c = threadIdx.x;
  int y = s / 48, x = s % 48;
  const float* fp = fsrc + ((size_t)item * 64 + c) * 9216;
#pragma unroll
  for (int p = 0; p < 3; p++)
#pragma unroll
    for (int q = 0; q < 3; q++){
      int yy = y + p - 1, xx = x + q - 1;
      float val = 0.f;
      if ((unsigned)yy < 48u && (unsigned)xx < 48u) val = fp[yy * 192 + xx * 2];
      uint16_t hi = f2h(val);
      int t = p * 3 + q;
      lds[c * 9 + t] = hi;
      lds[576 + c * 9 + t] = f2h(val - h2f(hi));
    }
  __syncthreads();
  uint32_t* d32 = (uint32_t*)(xb + ((size_t)item * 2304 + s) * 1152);
  const uint32_t* s32 = (const uint32_t*)lds;
#pragma unroll
  for (int k = 0; k < 9; k++){
    int idx = k * 64 + c;
    d32[idx] = s32[idx];
  }
}

// ---------------- correlation GEMM: Yt[s][o] = X @ Wn^T (XCD rectangle swizzle) ----------------

__launch_bounds__(256)
__global__ void k_gemm_corr(const uint16_t* __restrict__ A, const uint16_t* __restrict__ B,
                            float* __restrict__ Cd){
  __shared__ __align__(16) uint16_t As1[128 * 32];
  __shared__ __align__(16) uint16_t As2[128 * 32];
  __shared__ __align__(16) uint16_t Bs[128 * 32];
  int blk = blockIdx.x;                 // flat 1296 = 8 * 162
  int k8 = blk & 7, idx = blk >> 3;     // XCD k8 owns: item k8/2, n-half k8&1, all m
  int item = k8 >> 1;
  int n0 = ((k8 & 1) * 9 + idx % 9) * 128;
  int m0 = (idx / 9) * 128;
  const uint16_t* Ap = A + (size_t)item * 2304 * 1152;
  const uint16_t* Bp = B + (size_t)item * 2304 * 576;
  int tid = threadIdx.x;
  int wave = tid >> 6, lane = tid & 63, lm = lane & 15, lg = lane >> 4;
  int wy = wave >> 1, wx = wave & 1;
  int swl = (lg ^ ((lm >> 2) & 3)) * 8;
  f32x4 acc[4][4] = {};
  for (int kt = 0; kt < 18; kt++){
    int kb = kt * 32;
#pragma unroll
    for (int c = tid; c < 1536; c += 256){
      int half = c >> 9;            // 0=A_hi, 1=A_lo, 2=B
      int cc = c & 511;
      int row = cc >> 2, j = cc & 3;
      int sw = (j ^ ((row >> 2) & 3)) * 8;
      if (half == 0)
        gl_lds16(&Ap[(size_t)(m0 + row) * 1152 + kb + sw], &As1[cc * 8]);
      else if (half == 1)
        gl_lds16(&Ap[(size_t)(m0 + row) * 1152 + 576 + kb + sw], &As2[cc * 8]);
      else
        gl_lds16(&Bp[(size_t)(n0 + row) * 576 + kb + sw], &Bs[cc * 8]);
    }
    __syncthreads();
    half8 af1[4], af2[4], bf[4];
#pragma unroll
    for (int i = 0; i < 4; i++){
      af1[i] = *(const half8*)&As1[(wy * 64 + i * 16 + lm) * 32 + swl];
      af2[i] = *(const half8*)&As2[(wy * 64 + i * 16 + lm) * 32 + swl];
      bf[i]  = *(const half8*)&Bs[(wx * 64 + i * 16 + lm) * 32 + swl];
    }
#pragma unroll
    for (int i = 0; i < 4; i++)
#pragma unroll
      for (int j = 0; j < 4; j++){
        acc[i][j] = __builtin_amdgcn_mfma_f32_16x16x32_f16(af1[i], bf[j], acc[i][j], 0, 0, 0);
        acc[i][j] = __builtin_amdgcn_mfma_f32_16x16x32_f16(af2[i], bf[j], acc[i][j], 0, 0, 0);
      }
    __syncthreads();
  }
  float* Cp = Cd + (size_t)item * YI + 16;
#pragma unroll
  for (int i = 0; i < 4; i++){
    int rb = m0 + wy * 64 + i * 16 + lg * 4;
#pragma unroll
    for (int j = 0; j < 4; j++){
      int cc = n0 + wx * 64 + j * 16 + lm;
#pragma unroll
      for (int r = 0; r < 4; r++)
        Cp[(size_t)(rb + r) * 2320 + cc] = acc[i][j][r];
    }
  }
}

// ---------------- merged small kernels: Yt guards + Pt2 pad + Ybt2/Y1t2 zero + pack_w ----------------

__global__ void k_misc(float* __restrict__ Yt, uint16_t* __restrict__ pt2,
                       uint16_t* __restrict__ ybt2,
                       const float* __restrict__ w1, const float* __restrict__ w2,
                       uint16_t* __restrict__ p1, uint16_t* __restrict__ p2){
  int blk = blockIdx.x, tid = threadIdx.x;
  if (blk < 36){                         // Yt guard cols 2304..2319 + 16 front guards
    int t = blk * 256 + tid;             // [0, 9216)
    int item = t / 2304, row = t % 2304;
    float* yp = Yt + (size_t)item * YI + 16;
    f32x4 z = {};
#pragma unroll
    for (int q = 0; q < 4; q++) *(f32x4*)&yp[(size_t)row * 2320 + 2304 + 4 * q] = z;
    if (row < 16) (Yt + (size_t)item * YI)[row] = 0.f;
  } else if (blk < 820){                 // Pt2 pad rows
    int p = blk - 36;                    // [0, 784)
    int item = p / 196, pp = p % 196;
    int sy, sx;
    if (pp < 50){ sy = 0; sx = pp; }
    else if (pp < 100){ sy = 49; sx = pp - 50; }
    else if (pp < 148){ sy = pp - 99; sx = 0; }
    else { sy = pp - 147; sx = 49; }
    uint16_t* pr = pt2 + ((size_t)item * 2500 + sy * 50 + sx) * 2304;
    short8 z = {};
    for (int c = tid; c < 288; c += 256) *(short8*)&pr[c * 8] = z;
  } else if (blk < 3221){                // zero Ybt2+Y1t2 (contiguous 9,834,496 B)
    size_t i = ((size_t)(blk - 820) * 256 + tid) * 8;
    short8 z = {};
    *(short8*)&ybt2[i] = z;
  } else {                               // pack w1/w2 -> K-order bf16
    int i = (blk - 3221) * 256 + tid;    // [0, 36864)
    int co = i / 576, rem = i % 576, ci = rem / 9, t = rem % 9;
    int di = co * 576 + t * 64 + ci;
    p1[di] = f2b(w1[i]); p2[di] = f2b(w2[i]);
  }
}

// ---------------- merged fuse + softmax (branchless guarded gather) ----------------

__global__ void k_fuse_sm(const float* __restrict__ Yt, uint16_t* __restrict__ pt2){
  __shared__ float red[4];
  int bx = blockIdx.x;
  int s = (bx & 7) * 288 + (bx >> 3);   // XCD k owns contiguous s-window
  int item = blockIdx.y, t = threadIdx.x;
  const float* yp = Yt + (size_t)item * YI + 16;
  int rs[3]; rs[0] = gfun(s, -1); rs[1] = s; rs[2] = gfun(s, 1);
  int nact = (t < 64) ? 3 : 2;
  f32x4u v[3];
  for (int u = 0; u < 3; u++){
    f32x4u acc = {0.f, 0.f, 0.f, 0.f};
    if (u < nact){
      int g = t + u * 256;
      int o0 = 4 * g, orr = o0 / 48, oc0 = o0 % 48;
#pragma unroll
      for (int dd = 0; dd < 3; dd++){
        int a0 = rs[dd];
        if (a0 < 0) continue;               // block-uniform
        int d = dd - 1;
        int base; f32x4u mv = {1.f, 1.f, 1.f, 1.f};
        if (d == 0) base = o0;
        else {
          int tor = orr + d;
          if ((unsigned)tor < 48u) base = tor * 48 + oc0;
          else if (tor < 0){ base = 2255 + oc0; if (oc0 == 0) mv[0] = 0.f; }
          else { base = oc0 + 1; if (oc0 == 44) mv[3] = 0.f; }
        }
#pragma unroll
        for (int e = -1; e <= 1; e++){
          int a = a0 + e;
          if ((unsigned)a >= 2304u) continue;   // block-uniform
          const float* rowp = yp + (size_t)a * 2320;
          f32x4u x = *(const f32x4u*)&rowp[base + e];  // pad cols / front guards are zero
          acc += x * mv;
        }
      }
    }
    v[u] = acc;
  }
  float mx = -3.4e38f;
  for (int u = 0; u < nact; u++)
#pragma unroll
    for (int i = 0; i < 4; i++) mx = fmaxf(mx, v[u][i]);
#pragma unroll
  for (int off = 32; off > 0; off >>= 1) mx = fmaxf(mx, __shfl_xor(mx, off, 64));
  if ((t & 63) == 0) red[t >> 6] = mx;
  __syncthreads();
  mx = fmaxf(fmaxf(red[0], red[1]), fmaxf(red[2], red[3]));
  float sum = 0.f;
  for (int u = 0; u < nact; u++)
#pragma unroll
    for (int i = 0; i < 4; i++){ v[u][i] = __expf(10.f * (v[u][i] - mx)); sum += v[u][i]; }
#pragma unroll
  for (int off = 32; off > 0; off >>= 1) sum += __shfl_xor(sum, off, 64);
  __syncthreads();
  if ((t & 63) == 0) red[t >> 6] = sum;
  __syncthreads();
  float inv = 1.f / (red[0] + red[1] + red[2] + red[3]);
  uint16_t* pr = pt2 + ((size_t)item * 2500 + (size_t)(s / 48 + 1) * 50 + (s % 48) + 1) * 2304;
  for (int u = 0; u < nact; u++){
    s16x4 w;
#pragma unroll
    for (int i = 0; i < 4; i++) w[i] = (short)f2b(v[u][i] * inv);
    *(s16x4*)&pr[4 * (t + u * 256)] = w;
  }
}

// ---------------- raw 4x4 patch bank, layout [item][tap16][co][l] ----------------

__global__ void k_build_rwa(const float* __restrict__ bsrc, uint16_t* __restrict__ rwa){
  __shared__ uint16_t tile[64][66];
  int item = blockIdx.y, l0 = blockIdx.x * 64;
  const float* bp = bsrc + (size_t)item * 64 * 9216;
  int wave = threadIdx.x >> 6, lane = threadIdx.x & 63;
  for (int tap = 0; tap < 16; tap++){
    int py = tap >> 2, qx = tap & 3;
#pragma unroll
    for (int step = 0; step < 16; step++){
      int lsub = wave * 16 + step;
      int l = l0 + lsub, co = lane;
      int m = l * 64 + co;
      int c0 = m / 2304, rem = m % 2304, i = rem / 48, jj = rem % 48;
      int Y = 2 * i + py - 1, X = 2 * jj + qx - 1;
      float val = 0.f;
      if ((unsigned)Y < 96u && (unsigned)X < 96u) val = bp[(size_t)c0 * 9216 + Y * 96 + X];
      tile[lsub][co] = f2b(val);
    }
    __syncthreads();
#pragma unroll
    for (int step = 0; step < 16; step++){
      int co = wave * 16 + step;
      rwa[(((size_t)item * 16 + tap) * 64 + co) * 2304 + l0 + lane] = tile[lane][co];
    }
    __syncthreads();
  }
}

// ---------------- deconv GEMM: T = Rwa . Pt2^T, BK=64, XCD rectangle swizzle ----------------

__launch_bounds__(256)
__global__ void k_deconv2(const uint16_t* __restrict__ rwa, const uint16_t* __restrict__ pt2,
                          uint16_t* __restrict__ T){
  __shared__ __align__(16) uint16_t As[128 * 64];
  __shared__ __align__(16) uint16_t Bs[128 * 64];
  int blk = blockIdx.x;                 // flat 640 = 8 * 80
  int k8 = blk & 7, idx = blk >> 3;     // XCD k8: item k8/2, n-half k8&1, all m
  int item = k8 >> 1;
  int n0 = ((k8 & 1) * 10 + idx % 10) * 128;
  int m0 = (idx / 10) * 128;
  const uint16_t* Ap = rwa + (size_t)item * 1024 * 2304;
  const uint16_t* Bp = pt2 + (size_t)item * 2500 * 2304;   // rows >= 2500 read garbage; discarded
  int tid = threadIdx.x;
  int wave = tid >> 6, lane = tid & 63, lm = lane & 15, lg = lane >> 4;
  int wy = wave >> 1, wx = wave & 1;
  f32x4 acc[4][4] = {};
  for (int kt = 0; kt < 36; kt++){
    int kb = kt * 64;
#pragma unroll
    for (int c = tid; c < 2048; c += 256){
      int cc = c & 1023;
      int row = cc >> 3, pj = cc & 7;
      int jl = pj ^ (row & 7);           // 8-chunk XOR swizzle
      if (c < 1024)
        gl_lds16(&Ap[(size_t)(m0 + row) * 2304 + kb + jl * 8], &As[cc * 8]);
      else
        gl_lds16(&Bp[(size_t)(n0 + row) * 2304 + kb + jl * 8], &Bs[cc * 8]);
    }
    __syncthreads();
#pragma unroll
    for (int k2 = 0; k2 < 2; k2++){
      short8 af[4], bf[4];
#pragma unroll
      for (int i = 0; i < 4; i++){
        int rowa = wy * 64 + i * 16 + lm;
        int pja = (k2 * 4 + lg) ^ (lm & 7);
        af[i] = *(const short8*)&As[rowa * 64 + pja * 8];
        int rowb = wx * 64 + i * 16 + lm;
        bf[i] = *(const short8*)&Bs[rowb * 64 + pja * 8];
      }
#pragma unroll
      for (int i = 0; i < 4; i++)
#pragma unroll
        for (int j = 0; j < 4; j++)
          acc[i][j] = __builtin_amdgcn_mfma_f32_16x16x32_bf16(af[i], bf[j], acc[i][j], 0, 0, 0);
    }
    __syncthreads();
  }
  uint16_t* Tp = T + (size_t)item * 1024 * 2560;
#pragma unroll
  for (int i = 0; i < 4; i++){
    int rb = m0 + wy * 64 + i * 16 + lg * 4;
#pragma unroll
    for (int j = 0; j < 4; j++){
      int cc = n0 + wx * 64 + j * 16 + lm;
#pragma unroll
      for (int r = 0; r < 4; r++)
        Tp[(size_t)(rb + r) * 2560 + cc] = f2b(acc[i][j][r]);
    }
  }
}

// gather 4 taps per output pixel -> padded Ybt2[98][98][64] interior
__global__ void k_dred2(const uint16_t* __restrict__ T, uint16_t* __restrict__ ybt2){
  int my = blockIdx.x, phase = blockIdx.y, item = blockIdx.z;
  int co = threadIdx.x;
  int fy = phase >> 1, fx = phase & 1;
  const uint16_t* Tp = T + (size_t)item * 1024 * 2560;
  uint16_t* op = ybt2 + (size_t)item * 98 * 98 * 64;
  for (int mx = 0; mx < 48; mx++){
    float acc = 0.f;
#pragma unroll
    for (int ay = 0; ay < 2; ay++)
#pragma unroll
      for (int ax = 0; ax < 2; ax++){
        int tap = (3 - fy - 2 * ay) * 4 + (3 - fx - 2 * ax);
        int sp = (my + ay + fy) * 50 + (mx + ax + fx);
        acc += b2f(Tp[(size_t)(tap * 64 + co) * 2560 + sp]);
      }
    int Y = 2 * my + fy + 1, X = 2 * mx + fx + 1;
    op[((size_t)Y * 98 + X) * 64 + co] = f2b(acc * 0.25f);
  }
}

// ---------------- final 3x3 convs (direct from padded layout) ----------------

__launch_bounds__(256)
__global__ void k_conv_gemm2(const uint16_t* __restrict__ Wp, const uint16_t* __restrict__ Src,
                             const float* __restrict__ bias,
                             uint16_t* __restrict__ dst16, float* __restrict__ dst32){
  __shared__ __align__(16) uint16_t As[64 * 32];
  __shared__ __align__(16) uint16_t Bs[128 * 32];
  int n0 = blockIdx.x * 128, item = blockIdx.z;
  int tid = threadIdx.x, wave = tid >> 6, lane = tid & 63, lm = lane & 15, lg = lane >> 4;
  int swl = (lg ^ ((lm >> 2) & 3)) * 8;
  const uint16_t* Bp = Src + (size_t)item * 98 * 98 * 64;
  f32x4 acc[4][2] = {};
  for (int kt = 0; kt < 18; kt++){
    int t = kt >> 1, cb = (kt & 1) * 32;
    int py = t / 3, qx = t % 3;
#pragma unroll
    for (int c = tid; c < 768; c += 256){
      if (c < 256){
        int row = c >> 2, j = c & 3;
        int sw = (j ^ ((row >> 2) & 3)) * 8;
        gl_lds16(&Wp[(size_t)row * 576 + kt * 32 + sw], &As[c * 8]);
      } else {
        int cc = c - 256; int row = cc >> 2, j = cc & 3;
        int sw = (j ^ ((row >> 2) & 3)) * 8;
        int n = n0 + row; int y = n / 96, x = n % 96;
        gl_lds16(&Bp[((size_t)(y + py) * 98 + (x + qx)) * 64 + cb + sw], &Bs[cc * 8]);
      }
    }
    __syncthreads();
    short8 af[4], bf[2];
#pragma unroll
    for (int i = 0; i < 4; i++) af[i] = *(const short8*)&As[(i * 16 + lm) * 32 + swl];
#pragma unroll
    for (int j = 0; j < 2; j++) bf[j] = *(const short8*)&Bs[(wave * 32 + j * 16 + lm) * 32 + swl];
#pragma unroll
    for (int i = 0; i < 4; i++)
#pragma unroll
      for (int j = 0; j < 2; j++)
        acc[i][j] = __builtin_amdgcn_mfma_f32_16x16x32_bf16(af[i], bf[j], acc[i][j], 0, 0, 0);
    __syncthreads();
  }
  if (dst32){
#pragma unroll
    for (int i = 0; i < 4; i++)
#pragma unroll
      for (int j = 0; j < 2; j++){
        int n = n0 + wave * 32 + j * 16 + lm;
#pragma unroll
        for (int r = 0; r < 4; r++){
          int co = i * 16 + lg * 4 + r;
          dst32[((size_t)item * 64 + co) * 9216 + n] = acc[i][j][r] + bias[co];
        }
      }
  } else {
    uint16_t* dp = dst16 + (size_t)item * 98 * 98 * 64;
#pragma unroll
    for (int i = 0; i < 4; i++)
#pragma unroll
      for (int j = 0; j < 2; j++){
        int n = n0 + wave * 32 + j * 16 + lm;
        int y = n / 96, x = n % 96;
        int co0 = i * 16 + lg * 4;
        s16x4 w;
#pragma unroll
        for (int r = 0; r < 4; r++) w[r] = (short)f2b(acc[i][j][r] + bias[co0 + r]);
        *(s16x4*)&dp[((size_t)(y + 1) * 98 + (x + 1)) * 64 + co0] = w;
      }
  }
}

// ---------------- launch ----------------

extern "C" void kernel_launch(void* const* d_in, const int* in_sizes, int n_in,
                              void* d_out, int out_size, void* d_ws, size_t ws_size,
                              hipStream_t stream){
  const float* f  = (const float*)d_in[0];
  const float* b  = (const float*)d_in[1];
  const float* w1 = (const float*)d_in[2];
  const float* b1 = (const float*)d_in[3];
  const float* w2 = (const float*)d_in[4];
  const float* b2 = (const float*)d_in[5];
  char* ws = (char*)d_ws;
  float*    Yt   = (float*)ws;                          // 85,524,736 B (guard-padded)
  uint16_t* Wn   = (uint16_t*)(ws + 85524736ull);       // 10,616,832 B (phase1)
  uint16_t* Xb   = (uint16_t*)(ws + 96141568ull);       // 21,233,664 B (phase1)
  uint16_t* Pt2  = (uint16_t*)(ws + 85524736ull);       // 46,080,000 B (over dead Wn/Xb)
  uint16_t* Rwa  = (uint16_t*)(ws + 131604736ull);      // 18,874,368 B
  uint16_t* Ybt2 = (uint16_t*)(ws + 150479104ull);      //  4,917,248 B
  uint16_t* Y1t2 = (uint16_t*)(ws + 155396352ull);      //  4,917,248 B
  uint16_t* Wp1  = (uint16_t*)(ws + 160313600ull);      //     73,728 B
  uint16_t* Wp2  = (uint16_t*)(ws + 160387328ull);      //     73,728 B
  uint16_t* T    = (uint16_t*)ws;                       // 20,971,520 B (phase2, over dead Yt)
  float*    out  = (float*)d_out;

  k_build_wn<<<dim3(2304, 4), 64, 0, stream>>>(b, Wn);
  k_build_x<<<dim3(2304, 4), 64, 0, stream>>>(f, Xb);
  k_gemm_corr<<<dim3(1296), 256, 0, stream>>>(Xb, Wn, Yt);
  k_misc<<<dim3(3365), 256, 0, stream>>>(Yt, Pt2, Ybt2, w1, w2, Wp1, Wp2);  // Wn/Xb dead
  k_build_rwa<<<dim3(36, 4), 256, 0, stream>>>(b, Rwa);
  k_fuse_sm<<<dim3(2304, 4), 256, 0, stream>>>(Yt, Pt2);
  k_deconv2<<<dim3(640), 256, 0, stream>>>(Rwa, Pt2, T);          // Yt dead now
  k_dred2<<<dim3(48, 4, 4), 64, 0, stream>>>(T, Ybt2);
  k_conv_gemm2<<<dim3(72, 1, 4), 256, 0, stream>>>(Wp1, Ybt2, b1, Y1t2, nullptr);
  k_conv_gemm2<<<dim3(72, 1, 4), 256, 0, stream>>>(Wp2, Y1t2, b2, nullptr, out);
}

// Round 15
// 344.717 us; speedup vs baseline: 1.2316x; 1.0704x over previous
//
#include <hip/hip_runtime.h>
#include <stdint.h>

// ContextualAttention on MI355X. Inputs/outputs float32; correlation logits via
// 2-term f16 split MFMA (A=[x_hi|x_lo], B=w_hi), bf16 MFMA elsewhere, fp32 softmax.
//
// Round 15:
//  - T layout transposed to [sp][m]: deconv2 epilogue stores s16x4 (4 consecutive m
//    per lane); k_dred2 reads become 128B-contiguous per tap (was stride-5120B gather)
//  - k_conv_gemm2 BK=64: 9 iters x 16 MFMA/barrier, 8-chunk XOR swizzle
//  - mega k_build merges build_wn/build_x/build_rwa/Yt-guards/Ybt2-zero/pack_w;
//    Pt2 pad rows folded into k_fuse_sm extra blocks (block-uniform early path).
//    10 -> 7 launches.
//
// ws layout (bytes), budget 169,869,312:
//  Yt   [0, 85524736)            f32 padded logits (item stride 21,381,184; row 2320)
//  Wn   [85524736, +10616832)    f16 w_hi (phase1; dead after corr)
//  Xb   [96141568, +21233664)    f16 [hi|lo] (phase1; dead after corr)
//  Pt2  [85524736, +46080000)    bf16 padded softmax (over dead Wn/Xb)
//  Rwa  [131604736, +18874368)   bf16 4x4 patch bank
//  Ybt2 [150479104, +4917248)    bf16 padded deconv out
//  Y1t2 [155396352, +4917248)    bf16 padded conv1 out
//  Wp1  [160313600, +73728)  Wp2 [160387328, +73728)
//  phase2 over dead Yt: T [0, 20971520)  bf16 [item][sp 2560][m 1024]

#define YI 5345296ull   // floats per Yt item: 16 front guards + 2304*2320
typedef __attribute__((ext_vector_type(8))) short short8;
typedef __attribute__((ext_vector_type(8))) _Float16 half8;
typedef __attribute__((ext_vector_type(4))) float f32x4;
typedef __attribute__((ext_vector_type(4), aligned(4))) float f32x4u;
typedef __attribute__((ext_vector_type(4))) short s16x4;

#if defined(__has_builtin)
#if __has_builtin(__builtin_amdgcn_global_load_lds)
#define HAVE_GLL 1
#endif
#endif

#ifdef HAVE_GLL
typedef const __attribute__((address_space(1))) void* gp1_t;
typedef __attribute__((address_space(3))) void* lp3_t;
__device__ __forceinline__ void gl_lds16(const void* g, void* l){
  __builtin_amdgcn_global_load_lds((gp1_t)g, (lp3_t)l, 16, 0, 0);
}
#else
__device__ __forceinline__ void gl_lds16(const void* g, void* l){
  *(short8*)l = *(const short8*)g;
}
#endif

__device__ __forceinline__ float b2f(uint16_t u){
  union { uint32_t i; float f; } v; v.i = ((uint32_t)u) << 16; return v.f;
}
__device__ __forceinline__ uint16_t f2b(float f){
  uint32_t x = __float_as_uint(f);
  uint32_t r = (x + 0x7FFFu + ((x >> 16) & 1u)) >> 16;
  return (uint16_t)r;
}
__device__ __forceinline__ uint16_t f2h(float f){
  union { _Float16 h; uint16_t u; } v; v.h = (_Float16)f; return v.u;
}
__device__ __forceinline__ float h2f(uint16_t u){
  union { uint16_t u; _Float16 h; } v; v.u = u; return (float)v.h;
}
__device__ __forceinline__ int gfun(int x, int d){
  int t = (x % 48) * 48 + (x / 48) + d;
  if ((unsigned)t >= 2304u) return -1;
  return (t % 48) * 48 + (t / 48);
}

// ---------------- mega builder: wn, x, rwa, Yt guards, Ybt2 zero, pack_w ----------------

__global__ void k_build(const float* __restrict__ fsrc, const float* __restrict__ bsrc,
                        uint16_t* __restrict__ wn, uint16_t* __restrict__ xb,
                        uint16_t* __restrict__ rwa, float* __restrict__ Yt,
                        uint16_t* __restrict__ ybt2,
                        const float* __restrict__ w1, const float* __restrict__ w2,
                        uint16_t* __restrict__ p1, uint16_t* __restrict__ p2){
  __shared__ __align__(16) uint16_t shm[4608];   // 9216 B
  int blk = blockIdx.x, tid = threadIdx.x;
  if (blk < 2304){
    // build_wn: 4 (o,item) pairs per block, one per wave
    int p = blk * 4 + (tid >> 6), c = tid & 63;
    int o = p % 2304, item = p / 2304;
    int m = o * 64 + c;
    int c0 = m / 2304, rem = m % 2304, i = rem / 48, j = rem % 48;
    const float* bp = bsrc + ((size_t)item * 64 + c0) * 9216;
    float v[9]; float ss = 0.f;
#pragma unroll
    for (int pp = 0; pp < 3; pp++)
#pragma unroll
      for (int q = 0; q < 3; q++){
        int y = i + pp - 1, x = j + q - 1;
        float val = 0.f;
        if ((unsigned)y < 48u && (unsigned)x < 48u) val = bp[y * 192 + x * 2];
        v[pp * 3 + q] = val; ss += val * val;
      }
#pragma unroll
    for (int off = 32; off > 0; off >>= 1) ss += __shfl_xor(ss, off, 64);
    float inv = 1.f / fmaxf(sqrtf(ss), 1e-4f);
    uint16_t* lds = &shm[(tid >> 6) * 576];
#pragma unroll
    for (int t = 0; t < 9; t++) lds[c * 9 + t] = f2h(v[t] * inv);
    __syncthreads();
    uint32_t* d32 = (uint32_t*)(wn + ((size_t)item * 2304 + o) * 576);
    const uint32_t* s32 = (const uint32_t*)lds;
#pragma unroll
    for (int k = 0; k < 5; k++){
      int idx = k * 64 + c;
      if (idx < 288) d32[idx] = s32[idx];
    }
  } else if (blk < 4608){
    // build_x: 4 (s,item) pairs per block
    int p = (blk - 2304) * 4 + (tid >> 6), c = tid & 63;
    int s = p % 2304, item = p / 2304;
    int y = s / 48, x = s % 48;
    const float* fp = fsrc + ((size_t)item * 64 + c) * 9216;
    uint16_t* lds = &shm[(tid >> 6) * 1152];
#pragma unroll
    for (int pp = 0; pp < 3; pp++)
#pragma unroll
      for (int q = 0; q < 3; q++){
        int yy = y + pp - 1, xx = x + q - 1;
        float val = 0.f;
        if ((unsigned)yy < 48u && (unsigned)xx < 48u) val = fp[yy * 192 + xx * 2];
        uint16_t hi = f2h(val);
        int t = pp * 3 + q;
        lds[c * 9 + t] = hi;
        lds[576 + c * 9 + t] = f2h(val - h2f(hi));
      }
    __syncthreads();
    uint32_t* d32 = (uint32_t*)(xb + ((size_t)item * 2304 + s) * 1152);
    const uint32_t* s32 = (const uint32_t*)lds;
#pragma unroll
    for (int k = 0; k < 9; k++) d32[k * 64 + c] = s32[k * 64 + c];
  } else if (blk < 4752){
    // build_rwa
    uint16_t (*tile)[66] = (uint16_t(*)[66])shm;
    int bb = blk - 4608;
    int item = bb / 36, l0 = (bb % 36) * 64;
    const float* bp = bsrc + (size_t)item * 64 * 9216;
    int wave = tid >> 6, lane = tid & 63;
    for (int tap = 0; tap < 16; tap++){
      int py = tap >> 2, qx = tap & 3;
#pragma unroll
      for (int step = 0; step < 16; step++){
        int lsub = wave * 16 + step;
        int l = l0 + lsub, co = lane;
        int m = l * 64 + co;
        int c0 = m / 2304, rem = m % 2304, i = rem / 48, jj = rem % 48;
        int Y = 2 * i + py - 1, X = 2 * jj + qx - 1;
        float val = 0.f;
        if ((unsigned)Y < 96u && (unsigned)X < 96u) val = bp[(size_t)c0 * 9216 + Y * 96 + X];
        tile[lsub][co] = f2b(val);
      }
      __syncthreads();
#pragma unroll
      for (int step = 0; step < 16; step++){
        int co = wave * 16 + step;
        rwa[(((size_t)item * 16 + tap) * 64 + co) * 2304 + l0 + lane] = tile[lane][co];
      }
      __syncthreads();
    }
  } else if (blk < 4788){
    // Yt guard cols + front guards
    int t = (blk - 4752) * 256 + tid;   // [0, 9216)
    int item = t / 2304, row = t % 2304;
    float* yp = Yt + (size_t)item * YI + 16;
    f32x4 z = {};
#pragma unroll
    for (int q = 0; q < 4; q++) *(f32x4*)&yp[(size_t)row * 2320 + 2304 + 4 * q] = z;
    if (row < 16) (Yt + (size_t)item * YI)[row] = 0.f;
  } else if (blk < 7189){
    // zero Ybt2+Y1t2 (contiguous 9,834,496 B)
    size_t i = ((size_t)(blk - 4788) * 256 + tid) * 8;
    short8 z = {};
    *(short8*)&ybt2[i] = z;
  } else {
    // pack w1/w2 -> K-order bf16
    int i = (blk - 7189) * 256 + tid;   // [0, 36864)
    int co = i / 576, rem = i % 576, ci = rem / 9, t = rem % 9;
    int di = co * 576 + t * 64 + ci;
    p1[di] = f2b(w1[i]); p2[di] = f2b(w2[i]);
  }
}

// ---------------- correlation GEMM: Yt[s][o] = X @ Wn^T (XCD rectangle swizzle) ----------------

__launch_bounds__(256)
__global__ void k_gemm_corr(const uint16_t* __restrict__ A, const uint16_t* __restrict__ B,
                            float* __restrict__ Cd){
  __shared__ __align__(16) uint16_t As1[128 * 32];
  __shared__ __align__(16) uint16_t As2[128 * 32];
  __shared__ __align__(16) uint16_t Bs[128 * 32];
  int blk = blockIdx.x;                 // flat 1296 = 8 * 162
  int k8 = blk & 7, idx = blk >> 3;     // XCD k8: item k8/2, n-half k8&1, all m
  int item = k8 >> 1;
  int n0 = ((k8 & 1) * 9 + idx % 9) * 128;
  int m0 = (idx / 9) * 128;
  const uint16_t* Ap = A + (size_t)item * 2304 * 1152;
  const uint16_t* Bp = B + (size_t)item * 2304 * 576;
  int tid = threadIdx.x;
  int wave = tid >> 6, lane = tid & 63, lm = lane & 15, lg = lane >> 4;
  int wy = wave >> 1, wx = wave & 1;
  int swl = (lg ^ ((lm >> 2) & 3)) * 8;
  f32x4 acc[4][4] = {};
  for (int kt = 0; kt < 18; kt++){
    int kb = kt * 32;
#pragma unroll
    for (int c = tid; c < 1536; c += 256){
      int half = c >> 9;            // 0=A_hi, 1=A_lo, 2=B
      int cc = c & 511;
      int row = cc >> 2, j = cc & 3;
      int sw = (j ^ ((row >> 2) & 3)) * 8;
      if (half == 0)
        gl_lds16(&Ap[(size_t)(m0 + row) * 1152 + kb + sw], &As1[cc * 8]);
      else if (half == 1)
        gl_lds16(&Ap[(size_t)(m0 + row) * 1152 + 576 + kb + sw], &As2[cc * 8]);
      else
        gl_lds16(&Bp[(size_t)(n0 + row) * 576 + kb + sw], &Bs[cc * 8]);
    }
    __syncthreads();
    half8 af1[4], af2[4], bf[4];
#pragma unroll
    for (int i = 0; i < 4; i++){
      af1[i] = *(const half8*)&As1[(wy * 64 + i * 16 + lm) * 32 + swl];
      af2[i] = *(const half8*)&As2[(wy * 64 + i * 16 + lm) * 32 + swl];
      bf[i]  = *(const half8*)&Bs[(wx * 64 + i * 16 + lm) * 32 + swl];
    }
#pragma unroll
    for (int i = 0; i < 4; i++)
#pragma unroll
      for (int j = 0; j < 4; j++){
        acc[i][j] = __builtin_amdgcn_mfma_f32_16x16x32_f16(af1[i], bf[j], acc[i][j], 0, 0, 0);
        acc[i][j] = __builtin_amdgcn_mfma_f32_16x16x32_f16(af2[i], bf[j], acc[i][j], 0, 0, 0);
      }
    __syncthreads();
  }
  float* Cp = Cd + (size_t)item * YI + 16;
#pragma unroll
  for (int i = 0; i < 4; i++){
    int rb = m0 + wy * 64 + i * 16 + lg * 4;
#pragma unroll
    for (int j = 0; j < 4; j++){
      int cc = n0 + wx * 64 + j * 16 + lm;
#pragma unroll
      for (int r = 0; r < 4; r++)
        Cp[(size_t)(rb + r) * 2320 + cc] = acc[i][j][r];
    }
  }
}

// ---------------- merged fuse + softmax (+ Pt2 pad blocks) ----------------

__global__ void k_fuse_sm(const float* __restrict__ Yt, uint16_t* __restrict__ pt2){
  __shared__ float red[4];
  int bx = blockIdx.x;
  int item = blockIdx.y, t = threadIdx.x;
  if (bx >= 2304){                      // Pt2 pad rows (block-uniform path, no barrier)
    int pp = bx - 2304;                 // [0, 196)
    int sy, sx;
    if (pp < 50){ sy = 0; sx = pp; }
    else if (pp < 100){ sy = 49; sx = pp - 50; }
    else if (pp < 148){ sy = pp - 99; sx = 0; }
    else { sy = pp - 147; sx = 49; }
    uint16_t* pr = pt2 + ((size_t)item * 2500 + sy * 50 + sx) * 2304;
    short8 z = {};
    for (int c = t; c < 288; c += 256) *(short8*)&pr[c * 8] = z;
    return;
  }
  int s = (bx & 7) * 288 + (bx >> 3);   // XCD k owns contiguous s-window
  const float* yp = Yt + (size_t)item * YI + 16;
  int rs[3]; rs[0] = gfun(s, -1); rs[1] = s; rs[2] = gfun(s, 1);
  int nact = (t < 64) ? 3 : 2;
  f32x4u v[3];
  for (int u = 0; u < 3; u++){
    f32x4u acc = {0.f, 0.f, 0.f, 0.f};
    if (u < nact){
      int g = t + u * 256;
      int o0 = 4 * g, orr = o0 / 48, oc0 = o0 % 48;
#pragma unroll
      for (int dd = 0; dd < 3; dd++){
        int a0 = rs[dd];
        if (a0 < 0) continue;               // block-uniform
        int d = dd - 1;
        int base; f32x4u mv = {1.f, 1.f, 1.f, 1.f};
        if (d == 0) base = o0;
        else {
          int tor = orr + d;
          if ((unsigned)tor < 48u) base = tor * 48 + oc0;
          else if (tor < 0){ base = 2255 + oc0; if (oc0 == 0) mv[0] = 0.f; }
          else { base = oc0 + 1; if (oc0 == 44) mv[3] = 0.f; }
        }
#pragma unroll
        for (int e = -1; e <= 1; e++){
          int a = a0 + e;
          if ((unsigned)a >= 2304u) continue;   // block-uniform
          const float* rowp = yp + (size_t)a * 2320;
          f32x4u x = *(const f32x4u*)&rowp[base + e];  // pad cols / front guards are zero
          acc += x * mv;
        }
      }
    }
    v[u] = acc;
  }
  float mx = -3.4e38f;
  for (int u = 0; u < nact; u++)
#pragma unroll
    for (int i = 0; i < 4; i++) mx = fmaxf(mx, v[u][i]);
#pragma unroll
  for (int off = 32; off > 0; off >>= 1) mx = fmaxf(mx, __shfl_xor(mx, off, 64));
  if ((t & 63) == 0) red[t >> 6] = mx;
  __syncthreads();
  mx = fmaxf(fmaxf(red[0], red[1]), fmaxf(red[2], red[3]));
  float sum = 0.f;
  for (int u = 0; u < nact; u++)
#pragma unroll
    for (int i = 0; i < 4; i++){ v[u][i] = __expf(10.f * (v[u][i] - mx)); sum += v[u][i]; }
#pragma unroll
  for (int off = 32; off > 0; off >>= 1) sum += __shfl_xor(sum, off, 64);
  __syncthreads();
  if ((t & 63) == 0) red[t >> 6] = sum;
  __syncthreads();
  float inv = 1.f / (red[0] + red[1] + red[2] + red[3]);
  uint16_t* pr = pt2 + ((size_t)item * 2500 + (size_t)(s / 48 + 1) * 50 + (s % 48) + 1) * 2304;
  for (int u = 0; u < nact; u++){
    s16x4 w;
#pragma unroll
    for (int i = 0; i < 4; i++) w[i] = (short)f2b(v[u][i] * inv);
    *(s16x4*)&pr[4 * (t + u * 256)] = w;
  }
}

// ---------------- deconv GEMM: T[sp][m] = (Rwa . Pt2^T)^T, BK=64, XCD swizzle ----------------

__launch_bounds__(256)
__global__ void k_deconv2(const uint16_t* __restrict__ rwa, const uint16_t* __restrict__ pt2,
                          uint16_t* __restrict__ T){
  __shared__ __align__(16) uint16_t As[128 * 64];
  __shared__ __align__(16) uint16_t Bs[128 * 64];
  int blk = blockIdx.x;                 // flat 640 = 8 * 80
  int k8 = blk & 7, idx = blk >> 3;     // XCD k8: item k8/2, n-half k8&1, all m
  int item = k8 >> 1;
  int n0 = ((k8 & 1) * 10 + idx % 10) * 128;
  int m0 = (idx / 10) * 128;
  const uint16_t* Ap = rwa + (size_t)item * 1024 * 2304;
  const uint16_t* Bp = pt2 + (size_t)item * 2500 * 2304;   // rows >= 2500 read garbage; discarded
  int tid = threadIdx.x;
  int wave = tid >> 6, lane = tid & 63, lm = lane & 15, lg = lane >> 4;
  int wy = wave >> 1, wx = wave & 1;
  f32x4 acc[4][4] = {};
  for (int kt = 0; kt < 36; kt++){
    int kb = kt * 64;
#pragma unroll
    for (int c = tid; c < 2048; c += 256){
      int cc = c & 1023;
      int row = cc >> 3, pj = cc & 7;
      int jl = pj ^ (row & 7);           // 8-chunk XOR swizzle
      if (c < 1024)
        gl_lds16(&Ap[(size_t)(m0 + row) * 2304 + kb + jl * 8], &As[cc * 8]);
      else
        gl_lds16(&Bp[(size_t)(n0 + row) * 2304 + kb + jl * 8], &Bs[cc * 8]);
    }
    __syncthreads();
#pragma unroll
    for (int k2 = 0; k2 < 2; k2++){
      short8 af[4], bf[4];
#pragma unroll
      for (int i = 0; i < 4; i++){
        int rowa = wy * 64 + i * 16 + lm;
        int pja = (k2 * 4 + lg) ^ (lm & 7);
        af[i] = *(const short8*)&As[rowa * 64 + pja * 8];
        int rowb = wx * 64 + i * 16 + lm;
        bf[i] = *(const short8*)&Bs[rowb * 64 + pja * 8];
      }
#pragma unroll
      for (int i = 0; i < 4; i++)
#pragma unroll
        for (int j = 0; j < 4; j++)
          acc[i][j] = __builtin_amdgcn_mfma_f32_16x16x32_bf16(af[i], bf[j], acc[i][j], 0, 0, 0);
    }
    __syncthreads();
  }
  // epilogue: T[sp][m] — 4 consecutive m (r) per lane -> s16x4
  uint16_t* Tp = T + (size_t)item * 2560 * 1024;
#pragma unroll
  for (int i = 0; i < 4; i++){
    int rb = m0 + wy * 64 + i * 16 + lg * 4;
#pragma unroll
    for (int j = 0; j < 4; j++){
      int cc = n0 + wx * 64 + j * 16 + lm;
      s16x4 w;
#pragma unroll
      for (int r = 0; r < 4; r++) w[r] = (short)f2b(acc[i][j][r]);
      *(s16x4*)&Tp[(size_t)cc * 1024 + rb] = w;
    }
  }
}

// gather 4 taps per output pixel -> padded Ybt2[98][98][64] interior (coalesced T reads)
__global__ void k_dred2(const uint16_t* __restrict__ T, uint16_t* __restrict__ ybt2){
  int my = blockIdx.x, phase = blockIdx.y, item = blockIdx.z;
  int co = threadIdx.x;
  int fy = phase >> 1, fx = phase & 1;
  const uint16_t* Tp = T + (size_t)item * 2560 * 1024;
  uint16_t* op = ybt2 + (size_t)item * 98 * 98 * 64;
  for (int mx = 0; mx < 48; mx++){
    float acc = 0.f;
#pragma unroll
    for (int ay = 0; ay < 2; ay++)
#pragma unroll
      for (int ax = 0; ax < 2; ax++){
        int tap = (3 - fy - 2 * ay) * 4 + (3 - fx - 2 * ax);
        int sp = (my + ay + fy) * 50 + (mx + ax + fx);
        acc += b2f(Tp[(size_t)sp * 1024 + tap * 64 + co]);
      }
    int Y = 2 * my + fy + 1, X = 2 * mx + fx + 1;
    op[((size_t)Y * 98 + X) * 64 + co] = f2b(acc * 0.25f);
  }
}

// ---------------- final 3x3 convs: BK=64, 9 iters x 16 MFMA/barrier ----------------

__launch_bounds__(256)
__global__ void k_conv_gemm2(const uint16_t* __restrict__ Wp, const uint16_t* __restrict__ Src,
                             const float* __restrict__ bias,
                             uint16_t* __restrict__ dst16, float* __restrict__ dst32){
  __shared__ __align__(16) uint16_t As[64 * 64];
  __shared__ __align__(16) uint16_t Bs[128 * 64];
  int n0 = blockIdx.x * 128, item = blockIdx.z;
  int tid = threadIdx.x, wave = tid >> 6, lane = tid & 63, lm = lane & 15, lg = lane >> 4;
  const uint16_t* Bp = Src + (size_t)item * 98 * 98 * 64;
  f32x4 acc[4][2] = {};
  for (int t = 0; t < 9; t++){
    int py = t / 3, qx = t % 3;
#pragma unroll
    for (int c = tid; c < 1536; c += 256){
      if (c < 512){
        int row = c >> 3, pj = c & 7;
        int jl = pj ^ (row & 7);
        gl_lds16(&Wp[(size_t)row * 576 + t * 64 + jl * 8], &As[c * 8]);
      } else {
        int cc = c - 512; int row = cc >> 3, pj = cc & 7;
        int jl = pj ^ (row & 7);
        int n = n0 + row; int y = n / 96, x = n % 96;
        gl_lds16(&Bp[((size_t)(y + py) * 98 + (x + qx)) * 64 + jl * 8], &Bs[cc * 8]);
      }
    }
    __syncthreads();
#pragma unroll
    for (int k2 = 0; k2 < 2; k2++){
      short8 af[4], bf[2];
      int pja = (k2 * 4 + lg) ^ (lm & 7);
#pragma unroll
      for (int i = 0; i < 4; i++) af[i] = *(const short8*)&As[(i * 16 + lm) * 64 + pja * 8];
#pragma unroll
      for (int j = 0; j < 2; j++) bf[j] = *(const short8*)&Bs[(wave * 32 + j * 16 + lm) * 64 + pja * 8];
#pragma unroll
      for (int i = 0; i < 4; i++)
#pragma unroll
        for (int j = 0; j < 2; j++)
          acc[i][j] = __builtin_amdgcn_mfma_f32_16x16x32_bf16(af[i], bf[j], acc[i][j], 0, 0, 0);
    }
    __syncthreads();
  }
  if (dst32){
#pragma unroll
    for (int i = 0; i < 4; i++)
#pragma unroll
      for (int j = 0; j < 2; j++){
        int n = n0 + wave * 32 + j * 16 + lm;
#pragma unroll
        for (int r = 0; r < 4; r++){
          int co = i * 16 + lg * 4 + r;
          dst32[((size_t)item * 64 + co) * 9216 + n] = acc[i][j][r] + bias[co];
        }
      }
  } else {
    uint16_t* dp = dst16 + (size_t)item * 98 * 98 * 64;
#pragma unroll
    for (int i = 0; i < 4; i++)
#pragma unroll
      for (int j = 0; j < 2; j++){
        int n = n0 + wave * 32 + j * 16 + lm;
        int y = n / 96, x = n % 96;
        int co0 = i * 16 + lg * 4;
        s16x4 w;
#pragma unroll
        for (int r = 0; r < 4; r++) w[r] = (short)f2b(acc[i][j][r] + bias[co0 + r]);
        *(s16x4*)&dp[((size_t)(y + 1) * 98 + (x + 1)) * 64 + co0] = w;
      }
  }
}

// ---------------- launch ----------------

extern "C" void kernel_launch(void* const* d_in, const int* in_sizes, int n_in,
                              void* d_out, int out_size, void* d_ws, size_t ws_size,
                              hipStream_t stream){
  const float* f  = (const float*)d_in[0];
  const float* b  = (const float*)d_in[1];
  const float* w1 = (const float*)d_in[2];
  const float* b1 = (const float*)d_in[3];
  const float* w2 = (const float*)d_in[4];
  const float* b2 = (const float*)d_in[5];
  char* ws = (char*)d_ws;
  float*    Yt   = (float*)ws;                          // 85,524,736 B (guard-padded)
  uint16_t* Wn   = (uint16_t*)(ws + 85524736ull);       // 10,616,832 B (phase1)
  uint16_t* Xb   = (uint16_t*)(ws + 96141568ull);       // 21,233,664 B (phase1)
  uint16_t* Pt2  = (uint16_t*)(ws + 85524736ull);       // 46,080,000 B (over dead Wn/Xb)
  uint16_t* Rwa  = (uint16_t*)(ws + 131604736ull);      // 18,874,368 B
  uint16_t* Ybt2 = (uint16_t*)(ws + 150479104ull);      //  4,917,248 B
  uint16_t* Y1t2 = (uint16_t*)(ws + 155396352ull);      //  4,917,248 B
  uint16_t* Wp1  = (uint16_t*)(ws + 160313600ull);      //     73,728 B
  uint16_t* Wp2  = (uint16_t*)(ws + 160387328ull);      //     73,728 B
  uint16_t* T    = (uint16_t*)ws;                       // 20,971,520 B (phase2, over dead Yt)
  float*    out  = (float*)d_out;

  k_build<<<dim3(7333), 256, 0, stream>>>(f, b, Wn, Xb, Rwa, Yt, Ybt2, w1, w2, Wp1, Wp2);
  k_gemm_corr<<<dim3(1296), 256, 0, stream>>>(Xb, Wn, Yt);
  k_fuse_sm<<<dim3(2500, 4), 256, 0, stream>>>(Yt, Pt2);          // Wn/Xb dead; writes pads too
  k_deconv2<<<dim3(640), 256, 0, stream>>>(Rwa, Pt2, T);          // Yt dead now
  k_dred2<<<dim3(48, 4, 4), 64, 0, stream>>>(T, Ybt2);
  k_conv_gemm2<<<dim3(72, 1, 4), 256, 0, stream>>>(Wp1, Ybt2, b1, Y1t2, nullptr);
  k_conv_gemm2<<<dim3(72, 1, 4), 256, 0, stream>>>(Wp2, Y1t2, b2, nullptr, out);
}

// Round 16
// 296.579 us; speedup vs baseline: 1.4315x; 1.1623x over previous
//
#include <hip/hip_runtime.h>
#include <stdint.h>

// ContextualAttention on MI355X. Inputs/outputs float32; correlation logits via
// 2-term f16 split MFMA (A=[x_hi|x_lo], B=w_hi), bf16 MFMA elsewhere, fp32 softmax.
//
// Round 16: k_build load-imbalance fix — build_rwa split one-tap-per-block
// (4x16x36 = 2304 blocks, placed first in the block range) instead of 144 blocks
// serializing a 16-tap loop (78 us critical-path tail).
//
// ws layout (bytes), budget 169,869,312:
//  Yt   [0, 85524736)            f32 padded logits (item stride 21,381,184; row 2320)
//  Wn   [85524736, +10616832)    f16 w_hi (phase1; dead after corr)
//  Xb   [96141568, +21233664)    f16 [hi|lo] (phase1; dead after corr)
//  Pt2  [85524736, +46080000)    bf16 padded softmax (over dead Wn/Xb)
//  Rwa  [131604736, +18874368)   bf16 4x4 patch bank
//  Ybt2 [150479104, +4917248)    bf16 padded deconv out
//  Y1t2 [155396352, +4917248)    bf16 padded conv1 out
//  Wp1  [160313600, +73728)  Wp2 [160387328, +73728)
//  phase2 over dead Yt: T [0, 20971520)  bf16 [item][sp 2560][m 1024]

#define YI 5345296ull   // floats per Yt item: 16 front guards + 2304*2320
typedef __attribute__((ext_vector_type(8))) short short8;
typedef __attribute__((ext_vector_type(8))) _Float16 half8;
typedef __attribute__((ext_vector_type(4))) float f32x4;
typedef __attribute__((ext_vector_type(4), aligned(4))) float f32x4u;
typedef __attribute__((ext_vector_type(4))) short s16x4;

#if defined(__has_builtin)
#if __has_builtin(__builtin_amdgcn_global_load_lds)
#define HAVE_GLL 1
#endif
#endif

#ifdef HAVE_GLL
typedef const __attribute__((address_space(1))) void* gp1_t;
typedef __attribute__((address_space(3))) void* lp3_t;
__device__ __forceinline__ void gl_lds16(const void* g, void* l){
  __builtin_amdgcn_global_load_lds((gp1_t)g, (lp3_t)l, 16, 0, 0);
}
#else
__device__ __forceinline__ void gl_lds16(const void* g, void* l){
  *(short8*)l = *(const short8*)g;
}
#endif

__device__ __forceinline__ float b2f(uint16_t u){
  union { uint32_t i; float f; } v; v.i = ((uint32_t)u) << 16; return v.f;
}
__device__ __forceinline__ uint16_t f2b(float f){
  uint32_t x = __float_as_uint(f);
  uint32_t r = (x + 0x7FFFu + ((x >> 16) & 1u)) >> 16;
  return (uint16_t)r;
}
__device__ __forceinline__ uint16_t f2h(float f){
  union { _Float16 h; uint16_t u; } v; v.h = (_Float16)f; return v.u;
}
__device__ __forceinline__ float h2f(uint16_t u){
  union { uint16_t u; _Float16 h; } v; v.u = u; return (float)v.h;
}
__device__ __forceinline__ int gfun(int x, int d){
  int t = (x % 48) * 48 + (x / 48) + d;
  if ((unsigned)t >= 2304u) return -1;
  return (t % 48) * 48 + (t / 48);
}

// ---------------- mega builder: rwa (tap-split), wn, x, Yt guards, Ybt2 zero, pack_w ----------------

__global__ void k_build(const float* __restrict__ fsrc, const float* __restrict__ bsrc,
                        uint16_t* __restrict__ wn, uint16_t* __restrict__ xb,
                        uint16_t* __restrict__ rwa, float* __restrict__ Yt,
                        uint16_t* __restrict__ ybt2,
                        const float* __restrict__ w1, const float* __restrict__ w2,
                        uint16_t* __restrict__ p1, uint16_t* __restrict__ p2){
  __shared__ __align__(16) uint16_t shm[4608];   // 9216 B
  int blk = blockIdx.x, tid = threadIdx.x;
  if (blk < 2304){
    // build_rwa: one (item, tap, l0) per block
    uint16_t (*tile)[66] = (uint16_t(*)[66])shm;
    int item = blk / 576, rest = blk % 576;
    int tap = rest / 36, l0 = (rest % 36) * 64;
    const float* bp = bsrc + (size_t)item * 64 * 9216;
    int wave = tid >> 6, lane = tid & 63;
    int py = tap >> 2, qx = tap & 3;
#pragma unroll
    for (int step = 0; step < 16; step++){
      int lsub = wave * 16 + step;
      int l = l0 + lsub, co = lane;
      int m = l * 64 + co;
      int c0 = m / 2304, rem = m % 2304, i = rem / 48, jj = rem % 48;
      int Y = 2 * i + py - 1, X = 2 * jj + qx - 1;
      float val = 0.f;
      if ((unsigned)Y < 96u && (unsigned)X < 96u) val = bp[(size_t)c0 * 9216 + Y * 96 + X];
      tile[lsub][co] = f2b(val);
    }
    __syncthreads();
#pragma unroll
    for (int step = 0; step < 16; step++){
      int co = wave * 16 + step;
      rwa[(((size_t)item * 16 + tap) * 64 + co) * 2304 + l0 + lane] = tile[lane][co];
    }
  } else if (blk < 4608){
    // build_wn: 4 (o,item) pairs per block, one per wave
    int p = (blk - 2304) * 4 + (tid >> 6), c = tid & 63;
    int o = p % 2304, item = p / 2304;
    int m = o * 64 + c;
    int c0 = m / 2304, rem = m % 2304, i = rem / 48, j = rem % 48;
    const float* bp = bsrc + ((size_t)item * 64 + c0) * 9216;
    float v[9]; float ss = 0.f;
#pragma unroll
    for (int pp = 0; pp < 3; pp++)
#pragma unroll
      for (int q = 0; q < 3; q++){
        int y = i + pp - 1, x = j + q - 1;
        float val = 0.f;
        if ((unsigned)y < 48u && (unsigned)x < 48u) val = bp[y * 192 + x * 2];
        v[pp * 3 + q] = val; ss += val * val;
      }
#pragma unroll
    for (int off = 32; off > 0; off >>= 1) ss += __shfl_xor(ss, off, 64);
    float inv = 1.f / fmaxf(sqrtf(ss), 1e-4f);
    uint16_t* lds = &shm[(tid >> 6) * 576];
#pragma unroll
    for (int t = 0; t < 9; t++) lds[c * 9 + t] = f2h(v[t] * inv);
    __syncthreads();
    uint32_t* d32 = (uint32_t*)(wn + ((size_t)item * 2304 + o) * 576);
    const uint32_t* s32 = (const uint32_t*)lds;
#pragma unroll
    for (int k = 0; k < 5; k++){
      int idx = k * 64 + c;
      if (idx < 288) d32[idx] = s32[idx];
    }
  } else if (blk < 6912){
    // build_x: 4 (s,item) pairs per block
    int p = (blk - 4608) * 4 + (tid >> 6), c = tid & 63;
    int s = p % 2304, item = p / 2304;
    int y = s / 48, x = s % 48;
    const float* fp = fsrc + ((size_t)item * 64 + c) * 9216;
    uint16_t* lds = &shm[(tid >> 6) * 1152];
#pragma unroll
    for (int pp = 0; pp < 3; pp++)
#pragma unroll
      for (int q = 0; q < 3; q++){
        int yy = y + pp - 1, xx = x + q - 1;
        float val = 0.f;
        if ((unsigned)yy < 48u && (unsigned)xx < 48u) val = fp[yy * 192 + xx * 2];
        uint16_t hi = f2h(val);
        int t = pp * 3 + q;
        lds[c * 9 + t] = hi;
        lds[576 + c * 9 + t] = f2h(val - h2f(hi));
      }
    __syncthreads();
    uint32_t* d32 = (uint32_t*)(xb + ((size_t)item * 2304 + s) * 1152);
    const uint32_t* s32 = (const uint32_t*)lds;
#pragma unroll
    for (int k = 0; k < 9; k++) d32[k * 64 + c] = s32[k * 64 + c];
  } else if (blk < 6948){
    // Yt guard cols + front guards
    int t = (blk - 6912) * 256 + tid;   // [0, 9216)
    int item = t / 2304, row = t % 2304;
    float* yp = Yt + (size_t)item * YI + 16;
    f32x4 z = {};
#pragma unroll
    for (int q = 0; q < 4; q++) *(f32x4*)&yp[(size_t)row * 2320 + 2304 + 4 * q] = z;
    if (row < 16) (Yt + (size_t)item * YI)[row] = 0.f;
  } else if (blk < 9349){
    // zero Ybt2+Y1t2 (contiguous 9,834,496 B)
    size_t i = ((size_t)(blk - 6948) * 256 + tid) * 8;
    short8 z = {};
    *(short8*)&ybt2[i] = z;
  } else {
    // pack w1/w2 -> K-order bf16
    int i = (blk - 9349) * 256 + tid;   // [0, 36864)
    int co = i / 576, rem = i % 576, ci = rem / 9, t = rem % 9;
    int di = co * 576 + t * 64 + ci;
    p1[di] = f2b(w1[i]); p2[di] = f2b(w2[i]);
  }
}

// ---------------- correlation GEMM: Yt[s][o] = X @ Wn^T (XCD rectangle swizzle) ----------------

__launch_bounds__(256)
__global__ void k_gemm_corr(const uint16_t* __restrict__ A, const uint16_t* __restrict__ B,
                            float* __restrict__ Cd){
  __shared__ __align__(16) uint16_t As1[128 * 32];
  __shared__ __align__(16) uint16_t As2[128 * 32];
  __shared__ __align__(16) uint16_t Bs[128 * 32];
  int blk = blockIdx.x;                 // flat 1296 = 8 * 162
  int k8 = blk & 7, idx = blk >> 3;     // XCD k8: item k8/2, n-half k8&1, all m
  int item = k8 >> 1;
  int n0 = ((k8 & 1) * 9 + idx % 9) * 128;
  int m0 = (idx / 9) * 128;
  const uint16_t* Ap = A + (size_t)item * 2304 * 1152;
  const uint16_t* Bp = B + (size_t)item * 2304 * 576;
  int tid = threadIdx.x;
  int wave = tid >> 6, lane = tid & 63, lm = lane & 15, lg = lane >> 4;
  int wy = wave >> 1, wx = wave & 1;
  int swl = (lg ^ ((lm >> 2) & 3)) * 8;
  f32x4 acc[4][4] = {};
  for (int kt = 0; kt < 18; kt++){
    int kb = kt * 32;
#pragma unroll
    for (int c = tid; c < 1536; c += 256){
      int half = c >> 9;            // 0=A_hi, 1=A_lo, 2=B
      int cc = c & 511;
      int row = cc >> 2, j = cc & 3;
      int sw = (j ^ ((row >> 2) & 3)) * 8;
      if (half == 0)
        gl_lds16(&Ap[(size_t)(m0 + row) * 1152 + kb + sw], &As1[cc * 8]);
      else if (half == 1)
        gl_lds16(&Ap[(size_t)(m0 + row) * 1152 + 576 + kb + sw], &As2[cc * 8]);
      else
        gl_lds16(&Bp[(size_t)(n0 + row) * 576 + kb + sw], &Bs[cc * 8]);
    }
    __syncthreads();
    half8 af1[4], af2[4], bf[4];
#pragma unroll
    for (int i = 0; i < 4; i++){
      af1[i] = *(const half8*)&As1[(wy * 64 + i * 16 + lm) * 32 + swl];
      af2[i] = *(const half8*)&As2[(wy * 64 + i * 16 + lm) * 32 + swl];
      bf[i]  = *(const half8*)&Bs[(wx * 64 + i * 16 + lm) * 32 + swl];
    }
#pragma unroll
    for (int i = 0; i < 4; i++)
#pragma unroll
      for (int j = 0; j < 4; j++){
        acc[i][j] = __builtin_amdgcn_mfma_f32_16x16x32_f16(af1[i], bf[j], acc[i][j], 0, 0, 0);
        acc[i][j] = __builtin_amdgcn_mfma_f32_16x16x32_f16(af2[i], bf[j], acc[i][j], 0, 0, 0);
      }
    __syncthreads();
  }
  float* Cp = Cd + (size_t)item * YI + 16;
#pragma unroll
  for (int i = 0; i < 4; i++){
    int rb = m0 + wy * 64 + i * 16 + lg * 4;
#pragma unroll
    for (int j = 0; j < 4; j++){
      int cc = n0 + wx * 64 + j * 16 + lm;
#pragma unroll
      for (int r = 0; r < 4; r++)
        Cp[(size_t)(rb + r) * 2320 + cc] = acc[i][j][r];
    }
  }
}

// ---------------- merged fuse + softmax (+ Pt2 pad blocks) ----------------

__global__ void k_fuse_sm(const float* __restrict__ Yt, uint16_t* __restrict__ pt2){
  __shared__ float red[4];
  int bx = blockIdx.x;
  int item = blockIdx.y, t = threadIdx.x;
  if (bx >= 2304){                      // Pt2 pad rows (block-uniform path, no barrier)
    int pp = bx - 2304;                 // [0, 196)
    int sy, sx;
    if (pp < 50){ sy = 0; sx = pp; }
    else if (pp < 100){ sy = 49; sx = pp - 50; }
    else if (pp < 148){ sy = pp - 99; sx = 0; }
    else { sy = pp - 147; sx = 49; }
    uint16_t* pr = pt2 + ((size_t)item * 2500 + sy * 50 + sx) * 2304;
    short8 z = {};
    for (int c = t; c < 288; c += 256) *(short8*)&pr[c * 8] = z;
    return;
  }
  int s = (bx & 7) * 288 + (bx >> 3);   // XCD k owns contiguous s-window
  const float* yp = Yt + (size_t)item * YI + 16;
  int rs[3]; rs[0] = gfun(s, -1); rs[1] = s; rs[2] = gfun(s, 1);
  int nact = (t < 64) ? 3 : 2;
  f32x4u v[3];
  for (int u = 0; u < 3; u++){
    f32x4u acc = {0.f, 0.f, 0.f, 0.f};
    if (u < nact){
      int g = t + u * 256;
      int o0 = 4 * g, orr = o0 / 48, oc0 = o0 % 48;
#pragma unroll
      for (int dd = 0; dd < 3; dd++){
        int a0 = rs[dd];
        if (a0 < 0) continue;               // block-uniform
        int d = dd - 1;
        int base; f32x4u mv = {1.f, 1.f, 1.f, 1.f};
        if (d == 0) base = o0;
        else {
          int tor = orr + d;
          if ((unsigned)tor < 48u) base = tor * 48 + oc0;
          else if (tor < 0){ base = 2255 + oc0; if (oc0 == 0) mv[0] = 0.f; }
          else { base = oc0 + 1; if (oc0 == 44) mv[3] = 0.f; }
        }
#pragma unroll
        for (int e = -1; e <= 1; e++){
          int a = a0 + e;
          if ((unsigned)a >= 2304u) continue;   // block-uniform
          const float* rowp = yp + (size_t)a * 2320;
          f32x4u x = *(const f32x4u*)&rowp[base + e];  // pad cols / front guards are zero
          acc += x * mv;
        }
      }
    }
    v[u] = acc;
  }
  float mx = -3.4e38f;
  for (int u = 0; u < nact; u++)
#pragma unroll
    for (int i = 0; i < 4; i++) mx = fmaxf(mx, v[u][i]);
#pragma unroll
  for (int off = 32; off > 0; off >>= 1) mx = fmaxf(mx, __shfl_xor(mx, off, 64));
  if ((t & 63) == 0) red[t >> 6] = mx;
  __syncthreads();
  mx = fmaxf(fmaxf(red[0], red[1]), fmaxf(red[2], red[3]));
  float sum = 0.f;
  for (int u = 0; u < nact; u++)
#pragma unroll
    for (int i = 0; i < 4; i++){ v[u][i] = __expf(10.f * (v[u][i] - mx)); sum += v[u][i]; }
#pragma unroll
  for (int off = 32; off > 0; off >>= 1) sum += __shfl_xor(sum, off, 64);
  __syncthreads();
  if ((t & 63) == 0) red[t >> 6] = sum;
  __syncthreads();
  float inv = 1.f / (red[0] + red[1] + red[2] + red[3]);
  uint16_t* pr = pt2 + ((size_t)item * 2500 + (size_t)(s / 48 + 1) * 50 + (s % 48) + 1) * 2304;
  for (int u = 0; u < nact; u++){
    s16x4 w;
#pragma unroll
    for (int i = 0; i < 4; i++) w[i] = (short)f2b(v[u][i] * inv);
    *(s16x4*)&pr[4 * (t + u * 256)] = w;
  }
}

// ---------------- deconv GEMM: T[sp][m] = (Rwa . Pt2^T)^T, BK=64, XCD swizzle ----------------

__launch_bounds__(256)
__global__ void k_deconv2(const uint16_t* __restrict__ rwa, const uint16_t* __restrict__ pt2,
                          uint16_t* __restrict__ T){
  __shared__ __align__(16) uint16_t As[128 * 64];
  __shared__ __align__(16) uint16_t Bs[128 * 64];
  int blk = blockIdx.x;                 // flat 640 = 8 * 80
  int k8 = blk & 7, idx = blk >> 3;     // XCD k8: item k8/2, n-half k8&1, all m
  int item = k8 >> 1;
  int n0 = ((k8 & 1) * 10 + idx % 10) * 128;
  int m0 = (idx / 10) * 128;
  const uint16_t* Ap = rwa + (size_t)item * 1024 * 2304;
  const uint16_t* Bp = pt2 + (size_t)item * 2500 * 2304;   // rows >= 2500 read garbage; discarded
  int tid = threadIdx.x;
  int wave = tid >> 6, lane = tid & 63, lm = lane & 15, lg = lane >> 4;
  int wy = wave >> 1, wx = wave & 1;
  f32x4 acc[4][4] = {};
  for (int kt = 0; kt < 36; kt++){
    int kb = kt * 64;
#pragma unroll
    for (int c = tid; c < 2048; c += 256){
      int cc = c & 1023;
      int row = cc >> 3, pj = cc & 7;
      int jl = pj ^ (row & 7);           // 8-chunk XOR swizzle
      if (c < 1024)
        gl_lds16(&Ap[(size_t)(m0 + row) * 2304 + kb + jl * 8], &As[cc * 8]);
      else
        gl_lds16(&Bp[(size_t)(n0 + row) * 2304 + kb + jl * 8], &Bs[cc * 8]);
    }
    __syncthreads();
#pragma unroll
    for (int k2 = 0; k2 < 2; k2++){
      short8 af[4], bf[4];
#pragma unroll
      for (int i = 0; i < 4; i++){
        int rowa = wy * 64 + i * 16 + lm;
        int pja = (k2 * 4 + lg) ^ (lm & 7);
        af[i] = *(const short8*)&As[rowa * 64 + pja * 8];
        int rowb = wx * 64 + i * 16 + lm;
        bf[i] = *(const short8*)&Bs[rowb * 64 + pja * 8];
      }
#pragma unroll
      for (int i = 0; i < 4; i++)
#pragma unroll
        for (int j = 0; j < 4; j++)
          acc[i][j] = __builtin_amdgcn_mfma_f32_16x16x32_bf16(af[i], bf[j], acc[i][j], 0, 0, 0);
    }
    __syncthreads();
  }
  // epilogue: T[sp][m] — 4 consecutive m (r) per lane -> s16x4
  uint16_t* Tp = T + (size_t)item * 2560 * 1024;
#pragma unroll
  for (int i = 0; i < 4; i++){
    int rb = m0 + wy * 64 + i * 16 + lg * 4;
#pragma unroll
    for (int j = 0; j < 4; j++){
      int cc = n0 + wx * 64 + j * 16 + lm;
      s16x4 w;
#pragma unroll
      for (int r = 0; r < 4; r++) w[r] = (short)f2b(acc[i][j][r]);
      *(s16x4*)&Tp[(size_t)cc * 1024 + rb] = w;
    }
  }
}

// gather 4 taps per output pixel -> padded Ybt2[98][98][64] interior (coalesced T reads)
__global__ void k_dred2(const uint16_t* __restrict__ T, uint16_t* __restrict__ ybt2){
  int my = blockIdx.x, phase = blockIdx.y, item = blockIdx.z;
  int co = threadIdx.x;
  int fy = phase >> 1, fx = phase & 1;
  const uint16_t* Tp = T + (size_t)item * 2560 * 1024;
  uint16_t* op = ybt2 + (size_t)item * 98 * 98 * 64;
  for (int mx = 0; mx < 48; mx++){
    float acc = 0.f;
#pragma unroll
    for (int ay = 0; ay < 2; ay++)
#pragma unroll
      for (int ax = 0; ax < 2; ax++){
        int tap = (3 - fy - 2 * ay) * 4 + (3 - fx - 2 * ax);
        int sp = (my + ay + fy) * 50 + (mx + ax + fx);
        acc += b2f(Tp[(size_t)sp * 1024 + tap * 64 + co]);
      }
    int Y = 2 * my + fy + 1, X = 2 * mx + fx + 1;
    op[((size_t)Y * 98 + X) * 64 + co] = f2b(acc * 0.25f);
  }
}

// ---------------- final 3x3 convs: BK=64, 9 iters x 16 MFMA/barrier ----------------

__launch_bounds__(256)
__global__ void k_conv_gemm2(const uint16_t* __restrict__ Wp, const uint16_t* __restrict__ Src,
                             const float* __restrict__ bias,
                             uint16_t* __restrict__ dst16, float* __restrict__ dst32){
  __shared__ __align__(16) uint16_t As[64 * 64];
  __shared__ __align__(16) uint16_t Bs[128 * 64];
  int n0 = blockIdx.x * 128, item = blockIdx.z;
  int tid = threadIdx.x, wave = tid >> 6, lane = tid & 63, lm = lane & 15, lg = lane >> 4;
  const uint16_t* Bp = Src + (size_t)item * 98 * 98 * 64;
  f32x4 acc[4][2] = {};
  for (int t = 0; t < 9; t++){
    int py = t / 3, qx = t % 3;
#pragma unroll
    for (int c = tid; c < 1536; c += 256){
      if (c < 512){
        int row = c >> 3, pj = c & 7;
        int jl = pj ^ (row & 7);
        gl_lds16(&Wp[(size_t)row * 576 + t * 64 + jl * 8], &As[c * 8]);
      } else {
        int cc = c - 512; int row = cc >> 3, pj = cc & 7;
        int jl = pj ^ (row & 7);
        int n = n0 + row; int y = n / 96, x = n % 96;
        gl_lds16(&Bp[((size_t)(y + py) * 98 + (x + qx)) * 64 + jl * 8], &Bs[cc * 8]);
      }
    }
    __syncthreads();
#pragma unroll
    for (int k2 = 0; k2 < 2; k2++){
      short8 af[4], bf[2];
      int pja = (k2 * 4 + lg) ^ (lm & 7);
#pragma unroll
      for (int i = 0; i < 4; i++) af[i] = *(const short8*)&As[(i * 16 + lm) * 64 + pja * 8];
#pragma unroll
      for (int j = 0; j < 2; j++) bf[j] = *(const short8*)&Bs[(wave * 32 + j * 16 + lm) * 64 + pja * 8];
#pragma unroll
      for (int i = 0; i < 4; i++)
#pragma unroll
        for (int j = 0; j < 2; j++)
          acc[i][j] = __builtin_amdgcn_mfma_f32_16x16x32_bf16(af[i], bf[j], acc[i][j], 0, 0, 0);
    }
    __syncthreads();
  }
  if (dst32){
#pragma unroll
    for (int i = 0; i < 4; i++)
#pragma unroll
      for (int j = 0; j < 2; j++){
        int n = n0 + wave * 32 + j * 16 + lm;
#pragma unroll
        for (int r = 0; r < 4; r++){
          int co = i * 16 + lg * 4 + r;
          dst32[((size_t)item * 64 + co) * 9216 + n] = acc[i][j][r] + bias[co];
        }
      }
  } else {
    uint16_t* dp = dst16 + (size_t)item * 98 * 98 * 64;
#pragma unroll
    for (int i = 0; i < 4; i++)
#pragma unroll
      for (int j = 0; j < 2; j++){
        int n = n0 + wave * 32 + j * 16 + lm;
        int y = n / 96, x = n % 96;
        int co0 = i * 16 + lg * 4;
        s16x4 w;
#pragma unroll
        for (int r = 0; r < 4; r++) w[r] = (short)f2b(acc[i][j][r] + bias[co0 + r]);
        *(s16x4*)&dp[((size_t)(y + 1) * 98 + (x + 1)) * 64 + co0] = w;
      }
  }
}

// ---------------- launch ----------------

extern "C" void kernel_launch(void* const* d_in, const int* in_sizes, int n_in,
                              void* d_out, int out_size, void* d_ws, size_t ws_size,
                              hipStream_t stream){
  const float* f  = (const float*)d_in[0];
  const float* b  = (const float*)d_in[1];
  const float* w1 = (const float*)d_in[2];
  const float* b1 = (const float*)d_in[3];
  const float* w2 = (const float*)d_in[4];
  const float* b2 = (const float*)d_in[5];
  char* ws = (char*)d_ws;
  float*    Yt   = (float*)ws;                          // 85,524,736 B (guard-padded)
  uint16_t* Wn   = (uint16_t*)(ws + 85524736ull);       // 10,616,832 B (phase1)
  uint16_t* Xb   = (uint16_t*)(ws + 96141568ull);       // 21,233,664 B (phase1)
  uint16_t* Pt2  = (uint16_t*)(ws + 85524736ull);       // 46,080,000 B (over dead Wn/Xb)
  uint16_t* Rwa  = (uint16_t*)(ws + 131604736ull);      // 18,874,368 B
  uint16_t* Ybt2 = (uint16_t*)(ws + 150479104ull);      //  4,917,248 B
  uint16_t* Y1t2 = (uint16_t*)(ws + 155396352ull);      //  4,917,248 B
  uint16_t* Wp1  = (uint16_t*)(ws + 160313600ull);      //     73,728 B
  uint16_t* Wp2  = (uint16_t*)(ws + 160387328ull);      //     73,728 B
  uint16_t* T    = (uint16_t*)ws;                       // 20,971,520 B (phase2, over dead Yt)
  float*    out  = (float*)d_out;

  k_build<<<dim3(9493), 256, 0, stream>>>(f, b, Wn, Xb, Rwa, Yt, Ybt2, w1, w2, Wp1, Wp2);
  k_gemm_corr<<<dim3(1296), 256, 0, stream>>>(Xb, Wn, Yt);
  k_fuse_sm<<<dim3(2500, 4), 256, 0, stream>>>(Yt, Pt2);          // Wn/Xb dead; writes pads too
  k_deconv2<<<dim3(640), 256, 0, stream>>>(Rwa, Pt2, T);          // Yt dead now
  k_dred2<<<dim3(48, 4, 4), 64, 0, stream>>>(T, Ybt2);
  k_conv_gemm2<<<dim3(72, 1, 4), 256, 0, stream>>>(Wp1, Ybt2, b1, Y1t2, nullptr);
  k_conv_gemm2<<<dim3(72, 1, 4), 256, 0, stream>>>(Wp2, Y1t2, b2, nullptr, out);
}